// Round 17
// baseline (1034.817 us; speedup 1.0000x reference)
//
#include <hip/hip_runtime.h>
#include <hip/hip_bf16.h>
#include <math.h>

typedef __hip_bfloat16 bf16;
typedef __attribute__((ext_vector_type(8))) short bf16x8v;
typedef __attribute__((ext_vector_type(4))) float f32x4v;

#define BD 256   // batch
#define NN 128   // tokens
#define DM 256   // model dim
#define NHD 4    // heads
#define HDIM 64  // head dim
#define RR 3     // rounds

__device__ __forceinline__ float b2f(bf16 x) { return __bfloat162float(x); }
__device__ __forceinline__ bf16 f2b(float x) { return __float2bfloat16(x); }
__device__ __forceinline__ float geluf(float x) { return 0.5f * x * (1.f + erff(x * 0.70710678118654752f)); }

#define GLOAD16(g, l) __builtin_amdgcn_global_load_lds( \
    (const __attribute__((address_space(1))) void*)(g), \
    (__attribute__((address_space(3))) void*)(l), 16, 0, 0)

// fp32 -> bf16 convert
__global__ __launch_bounds__(256) void cvt32to16_kernel(
    const float* __restrict__ in, bf16* __restrict__ out, int n)
{
  int i = blockIdx.x * 256 + threadIdx.x;
  int stride = gridDim.x * 256;
  for (; i < n; i += stride) out[i] = f2b(in[i]);
}

// bf16 -> fp32
__global__ __launch_bounds__(256) void cvt16to32_kernel(
    const bf16* __restrict__ in, float* __restrict__ out, int n)
{
  int i = blockIdx.x * 256 + threadIdx.x;
  int stride = gridDim.x * 256;
  for (; i < n; i += stride) out[i] = b2f(in[i]);
}

// ---------------------------------------------------------------------------
// Batched weight transpose: src fp32 [*][256] row-major -> dst bf16 [256][K].
// ---------------------------------------------------------------------------
struct TDesc { const float* src; bf16* dst; int K; int base; };
struct TTable { TDesc e[12]; };

__global__ __launch_bounds__(256) void transpose_w_kernel(TTable T, int nent)
{
  int t = blockIdx.x;
  int ei = 0;
  for (int i = 1; i < nent; i++) if (t >= T.e[i].base) ei = i;
  const float* src = T.e[ei].src;
  bf16* dst = T.e[ei].dst;
  int K = T.e[ei].K;
  int lt = t - T.e[ei].base;
  int nt = lt & 7, kt = lt >> 3;

  __shared__ float tile[32][33];
  int tx = threadIdx.x & 31, ty = threadIdx.x >> 5;
#pragma unroll
  for (int i = 0; i < 4; i++)
    tile[ty + i * 8][tx] = src[(size_t)(kt * 32 + ty + i * 8) * 256 + nt * 32 + tx];
  __syncthreads();
#pragma unroll
  for (int i = 0; i < 4; i++)
    dst[(size_t)(nt * 32 + ty + i * 8) * K + kt * 32 + tx] = f2b(tile[tx][ty + i * 8]);
}

// ---------------------------------------------------------------------------
// Weight-fuse: outT[col][koff+k] = f2b( sum_m A[k][m] * B[m][col] ), 256x256.
// ---------------------------------------------------------------------------
struct FJob { const float* A; const float* B; bf16* outT; int koff; int kst; };
struct FJobs { FJob j[13]; };

__global__ __launch_bounds__(256) void wfuse_kernel(FJobs F)
{
  const FJob jb = F.j[blockIdx.y];
  const int k0 = blockIdx.x * 16;
  const int col = threadIdx.x;
  float acc[16];
#pragma unroll
  for (int i = 0; i < 16; i++) acc[i] = 0.f;
  for (int m = 0; m < 256; m++) {
    float bv = jb.B[(size_t)m * 256 + col];
#pragma unroll
    for (int i = 0; i < 16; i++)
      acc[i] += jb.A[(size_t)(k0 + i) * 256 + m] * bv;
  }
#pragma unroll
  for (int i = 0; i < 16; i++)
    jb.outT[(size_t)col * jb.kst + jb.koff + k0 + i] = f2b(acc[i]);
}

// ---------------------------------------------------------------------------
// Bias-fuse: blocks 0..5 -> fgb/ftb per round; block 6 -> fab_bias, vha, cha.
// ---------------------------------------------------------------------------
__global__ __launch_bounds__(256) void bfuse_kernel(
    const float* gate_w, const float* tr_w, const float* gate_b, const float* tr_b,
    const float* ha_b, const float* sa_b,
    const float* ahw, const float* ahb, const float* bil,
    const float* bhw, const float* bhb,
    float* fgb, float* ftb, float* fab_bias, float* vha, float* cha)
{
  int blk = blockIdx.x, col = threadIdx.x;
  if (blk < 6) {
    int r = blk >> 1; bool isT = blk & 1;
    const float* W  = (isT ? tr_w : gate_w) + (size_t)r * 262144;
    const float* b0 = (isT ? tr_b : gate_b) + (size_t)r * 256;
    const float* boh = ha_b + (size_t)r * 1024 + 768;
    const float* bos = sa_b + (size_t)r * 1024 + 768;
    float acc = b0[col];
    for (int m = 0; m < 256; m++) {
      acc += boh[m] * W[(size_t)(256 + m) * 256 + col];
      acc += bos[m] * W[(size_t)(768 + m) * 256 + col];
    }
    ((isT ? ftb : fgb) + (size_t)r * 256)[col] = acc;
  } else {
    float a1 = 0.f, a2 = 0.f;
    for (int m = 0; m < 256; m++) {
      a1 += ahb[m] * bil[(size_t)m * 256 + col];
      a2 += ahw[(size_t)col * 256 + m] * bhw[m];
    }
    fab_bias[col] = a1;
    vha[col] = a2;
    if (col == 0) {
      float c = bhb[0];
      for (int m = 0; m < 256; m++) c += ahb[m] * bhw[m];
      cha[0] = c;
    }
  }
}

// ---------------------------------------------------------------------------
// proj_fused v6 (T4 counted-vmcnt, barrier-free k-loop):
// grid 512 = (b, colhalf), block 256 = 4 waves (r13 wave map: 64x64 tiles).
// A full [128][256] 64KB @0, staged once, ONE barrier, read-only after.
// W: WAVE-PRIVATE 4KB panels (own 64 cols x 32k), 3-buffer ring @65536+w*12288.
// Loop: s_waitcnt vmcnt(8) (tiles t+1,t+2 in flight) -> reads -> 16 MFMA ->
// issue tile t+3 into just-freed buffer. No __syncthreads in loop.
// ct job's CA half (global A loads) uses vmcnt(0) for those 8 steps.
// jobs: 0 haQ, 1 haK(g), 2 haV(g,tr), 3 saQ, 4 saK, 5 saV(tr), 6 ct(gelu).
// ---------------------------------------------------------------------------
struct ProjArgs {
  const bf16* Hc; const bf16* CA; const int* gather;
  const bf16* W[7];
  const float* bias[7];
  bf16* out[7];
};

__global__ __launch_bounds__(256) void proj_fused_kernel(ProjArgs P)
{
  const int b  = blockIdx.x & 255;
  const int nh = blockIdx.x >> 8;
  const int c0 = nh * 128;
  const int tid = threadIdx.x;
  const int w = tid >> 6;
  const int lane = tid & 63;
  const int wr = w >> 1, wc = w & 1;
  const int r16 = lane & 15;
  const int kg = lane >> 4;

  __shared__ __align__(16) char lds[114688];
  // A 64KB @0 ; wave-private W ring @ 65536 + w*12288 (3 bufs x 4KB).

  const char* Hb = (const char*)(P.Hc + (size_t)b * NN * DM);

  // ---- stage full-K A tile (r13-proven), pre-swizzled source ----
#pragma unroll
  for (int i = 0; i < 16; i++) {
    int row = w * 32 + i * 2 + (lane >> 5);
    int src = row * 512 + (((lane & 31) * 16) ^ ((row & 7) << 4));
    GLOAD16(Hb + src, lds + w * 16384 + i * 1024);
  }

  const int WB = 65536 + w * 12288;
  const int wcol0 = c0 + wc * 64;   // this wave's global col base

  // Wave-private W tile issue: 4 GLOAD16 = 4KB = [64 cols][32k], slot-swizzled.
#define ISSUE_W(WT, K2B, KTL, BUF) do { \
    _Pragma("unroll") \
    for (int i_ = 0; i_ < 4; i_++) { \
      int lc_ = i_ * 16 + (lane >> 2); \
      int sl_ = (lane & 3) ^ ((lc_ >> 1) & 3); \
      GLOAD16((const char*)(WT) + (size_t)(wcol0 + lc_) * (K2B) + (KTL) * 64 + sl_ * 16, \
              lds + WB + (BUF) * 4096 + i_ * 1024); \
    } } while (0)

  // prologue: tiles 0,1,2 (job 0, kt 0..2)
  ISSUE_W(P.W[0], 512, 0, 0);
  ISSUE_W(P.W[0], 512, 1, 1);
  ISSUE_W(P.W[0], 512, 2, 2);
  __syncthreads();   // the ONLY barrier: A visible; drains all (count = 0)

  int lrow[4], grow[4];
#pragma unroll
  for (int mi = 0; mi < 4; mi++) {
    lrow[mi] = wr * 64 + mi * 16 + r16;
    int g = P.gather[b * NN + lrow[mi]];
    grow[mi] = min(max(g, 0), NN - 1);
  }
  int wro[4];
#pragma unroll
  for (int ni = 0; ni < 4; ni++) {
    int lc = ni * 16 + r16;   // local col within wave panel
    wro[ni] = lc * 64 + ((kg ^ ((lc >> 1) & 3)) << 4);
  }

  const bf16* CAb = P.CA + (size_t)b * NN * DM;
  int buf = 0;
  f32x4v zero = {0.f, 0.f, 0.f, 0.f};

#pragma unroll
  for (int j = 0; j < 7; j++) {
    const bool GATH = (j == 1) || (j == 2);
    const bool TR   = (j == 2) || (j == 5);
    const bool ACT  = (j == 6);
    const int NKS = (j == 6) ? 16 : 8;
    const int K2B = (j == 6) ? 1024 : 512;   // W row stride bytes
    const bf16* Wj  = P.W[j];
    const bf16* Wj1 = (j < 6) ? P.W[j + 1] : P.W[j];
    const int  K2Bn = (j < 6) ? ((j + 1 == 6) ? 1024 : 512) : K2B;

    f32x4v acc[4][4];
#pragma unroll
    for (int mi = 0; mi < 4; mi++)
#pragma unroll
      for (int ni = 0; ni < 4; ni++) acc[mi][ni] = zero;

    for (int kt = 0; kt < NKS; kt++) {
      bf16x8v a[4], wv[4];
      if (j == 6 && kt >= 8) {
        // ct high-K half: A from CA (global register loads), then full drain.
#pragma unroll
        for (int mi = 0; mi < 4; mi++)
          a[mi] = *(const bf16x8v*)(CAb + (size_t)lrow[mi] * DM + (kt - 8) * 32 + kg * 8);
        asm volatile("s_waitcnt vmcnt(0)" ::: "memory");
        __builtin_amdgcn_sched_barrier(0);
      } else {
        // counted wait: tiles t+1, t+2 (8 loads) may stay in flight.
        asm volatile("s_waitcnt vmcnt(8)" ::: "memory");
        __builtin_amdgcn_sched_barrier(0);
#pragma unroll
        for (int mi = 0; mi < 4; mi++) {
          int ar = GATH ? grow[mi] : lrow[mi];
          int off = ar * 512 + (((kt * 64) + kg * 16) ^ ((ar & 7) << 4));
          a[mi] = *(const bf16x8v*)(lds + off);
        }
      }
#pragma unroll
      for (int ni = 0; ni < 4; ni++)
        wv[ni] = *(const bf16x8v*)(lds + WB + buf * 4096 + wro[ni]);

#pragma unroll
      for (int mi = 0; mi < 4; mi++)
#pragma unroll
        for (int ni = 0; ni < 4; ni++)
          acc[mi][ni] = __builtin_amdgcn_mfma_f32_16x16x32_bf16(a[mi], wv[ni], acc[mi][ni], 0, 0, 0);

      __builtin_amdgcn_sched_barrier(0);   // keep issue below the reads above

      // issue tile t+3 into the buffer just consumed (ring distance 3)
      int nkt = kt + 3;
      if (nkt < NKS) {
        ISSUE_W(Wj, K2B, nkt, buf);
      } else if (j < 6) {
        ISSUE_W(Wj1, K2Bn, nkt - NKS, buf);
      }
      buf = (buf + 1) % 3;
    }

    // ---- epilogue for job j (r13-proven layout) ----
    bf16* outj = P.out[j];
    const float* bj = P.bias[j];
#pragma unroll
    for (int ni = 0; ni < 4; ni++) {
      int col = c0 + wc * 64 + ni * 16 + r16;
      float bv = bj ? bj[col] : 0.f;
#pragma unroll
      for (int mi = 0; mi < 4; mi++) {
        int row0 = wr * 64 + mi * 16 + kg * 4;
        if (!TR) {
          size_t base = ((size_t)b * NN + row0) * DM + col;
#pragma unroll
          for (int r = 0; r < 4; r++) {
            float x = acc[mi][ni][r] + bv;
            if (ACT) x = geluf(x);
            outj[base + (size_t)r * DM] = f2b(x);
          }
        } else {
          size_t base = ((size_t)b * DM + col) * NN + row0;
#pragma unroll
          for (int r = 0; r < 4; r++)
            outj[base + r] = f2b(acc[mi][ni][r] + bv);
        }
      }
    }
  }
#undef ISSUE_W
}

// ---------------------------------------------------------------------------
// dualw_gemm: TWO GEMMs sharing A (r13-verified). 8 waves: 0-3 -> W0, 4-7 -> W1.
// ---------------------------------------------------------------------------
struct DJob {
  const bf16 *a0, *a1, *a2, *a3;
  const bf16 *W0, *W1;
  const float *b0, *b1;
  bf16 *o0, *o1;
  int K;
};

__global__ __launch_bounds__(512) void dualw_gemm_kernel(DJob jb)
{
  const int b  = blockIdx.x & 255;
  const int nh = blockIdx.x >> 8;
  const int c0 = nh * 128;
  const int tid = threadIdx.x;
  const int w = tid >> 6;
  const int jj = w >> 2;
  const int wsub = w & 3;
  const int wr = wsub >> 1, wc = wsub & 1;
  const int lane = tid & 63;
  const int r16 = lane & 15;
  const int kg = lane >> 4;
  const int K = jb.K;
  const int nk = K >> 5;

  __shared__ __align__(16) char lds[49152];

  const int srow = tid >> 2;
  const int skc  = tid & 3;
  const int sl   = skc ^ ((srow >> 1) & 3);
  const size_t aoff = ((size_t)b * NN + srow) * DM + sl * 8;
  const bf16* w0src = jb.W0 + (size_t)(c0 + srow) * K + sl * 8;
  const bf16* w1src = jb.W1 + (size_t)(c0 + srow) * K + sl * 8;
  const int wbase = w * 1024;

  f32x4v zero = {0.f, 0.f, 0.f, 0.f};
  f32x4v acc[4][4];
#pragma unroll
  for (int mi = 0; mi < 4; mi++)
#pragma unroll
    for (int ni = 0; ni < 4; ni++) acc[mi][ni] = zero;

  int a_ro[4], w_ro[4];
#pragma unroll
  for (int mi = 0; mi < 4; mi++) {
    int row = wr * 64 + mi * 16 + r16;
    a_ro[mi] = row * 64 + ((kg ^ ((row >> 1) & 3)) << 4);
  }
  const int wsel = 16384 + jj * 16384;
#pragma unroll
  for (int ni = 0; ni < 4; ni++) {
    int col = wc * 64 + ni * 16 + r16;
    w_ro[ni] = col * 64 + ((kg ^ ((col >> 1) & 3)) << 4);
  }

  {
    GLOAD16(jb.a0 + aoff, lds + wbase);
    GLOAD16(w0src,        lds + 16384 + wbase);
    GLOAD16(w1src,        lds + 32768 + wbase);
  }
  __syncthreads();

  int cur = 0;
  for (int kt = 0; kt < nk; kt++) {
    if (kt + 1 < nk) {
      int k0 = (kt + 1) << 5;
      int sg = k0 >> 8;
      const bf16* Ab = (sg == 0) ? jb.a0 : ((sg == 1) ? jb.a1 : ((sg == 2) ? jb.a2 : jb.a3));
      int ko = k0 & 255;
      int nb = (cur ^ 1) * 8192;
      GLOAD16(Ab + aoff + ko,  lds + nb + wbase);
      GLOAD16(w0src + k0,      lds + 16384 + nb + wbase);
      GLOAD16(w1src + k0,      lds + 32768 + nb + wbase);
    }

    const char* La = lds + cur * 8192;
    const char* Lw = lds + wsel + cur * 8192;
    bf16x8v a[4], ww[4];
#pragma unroll
    for (int mi = 0; mi < 4; mi++) a[mi] = *(const bf16x8v*)(La + a_ro[mi]);
#pragma unroll
    for (int ni = 0; ni < 4; ni++) ww[ni] = *(const bf16x8v*)(Lw + w_ro[ni]);
#pragma unroll
    for (int mi = 0; mi < 4; mi++)
#pragma unroll
      for (int ni = 0; ni < 4; ni++)
        acc[mi][ni] = __builtin_amdgcn_mfma_f32_16x16x32_bf16(a[mi], ww[ni], acc[mi][ni], 0, 0, 0);

    __syncthreads();
    cur ^= 1;
  }

  bf16* out = jj ? jb.o1 : jb.o0;
  const float* bias = jj ? jb.b1 : jb.b0;
#pragma unroll
  for (int ni = 0; ni < 4; ni++) {
    int col = c0 + wc * 64 + ni * 16 + r16;
    float bv = bias ? bias[col] : 0.f;
#pragma unroll
    for (int mi = 0; mi < 4; mi++) {
      int row0 = wr * 64 + mi * 16 + kg * 4;
      size_t base = ((size_t)b * NN + row0) * DM + col;
#pragma unroll
      for (int r = 0; r < 4; r++)
        out[base + (size_t)r * DM] = f2b(acc[mi][ni][r] + bv);
    }
  }
}

// ---------------------------------------------------------------------------
// Fused dual MFMA attention — r8-verified.
// ---------------------------------------------------------------------------
struct AttnArgs {
  const bf16 *Qa, *Ka, *Va; bf16* Oa;
  const bf16 *Qs, *Ks, *Vs; bf16* Os;
};

__global__ __launch_bounds__(256) void attn2_kernel(
    AttnArgs A, const int* __restrict__ ph, const float* __restrict__ mask)
{
  const int b = blockIdx.y, h = blockIdx.x;
  const bool has_mask = (blockIdx.z == 1);
  const bf16* Qb = has_mask ? A.Qs : A.Qa;
  const bf16* Kb = has_mask ? A.Ks : A.Ka;
  const bf16* Vt = has_mask ? A.Vs : A.Va;
  bf16* Ob       = has_mask ? A.Os : A.Oa;

  const int w = threadIdx.x >> 6;
  const int lane = threadIdx.x & 63;
  const int r16 = lane & 15, kg = lane >> 4;
  const int q0 = w * 32;

  __shared__ bf16 P_lds[4][32 * 128];
  __shared__ int   ph_sh[NN];
  __shared__ float mk_sh[NN];

  if (has_mask && threadIdx.x < NN) {
    ph_sh[threadIdx.x] = ph[(size_t)b * NN + threadIdx.x];
    mk_sh[threadIdx.x] = mask[(size_t)b * NN + threadIdx.x];
  }
  __syncthreads();

  const bf16* Qh = Qb + (size_t)b * NN * DM + (size_t)h * HDIM;
  const bf16* Kh = Kb + (size_t)b * NN * DM + (size_t)h * HDIM;
  const bf16* Vh = Vt + ((size_t)b * DM + (size_t)h * HDIM) * NN;

  f32x4v zero = {0.f, 0.f, 0.f, 0.f};

  f32x4v accs[2][8];
#pragma unroll
  for (int mi = 0; mi < 2; mi++)
#pragma unroll
    for (int ni = 0; ni < 8; ni++) accs[mi][ni] = zero;

#pragma unroll
  for (int ks = 0; ks < 2; ks++) {
    int d = ks * 32 + kg * 8;
    bf16x8v a[2], bb[8];
#pragma unroll
    for (int mi = 0; mi < 2; mi++)
      a[mi] = *(const bf16x8v*)(Qh + (size_t)(q0 + mi * 16 + r16) * DM + d);
#pragma unroll
    for (int ni = 0; ni < 8; ni++)
      bb[ni] = *(const bf16x8v*)(Kh + (size_t)(ni * 16 + r16) * DM + d);
#pragma unroll
    for (int mi = 0; mi < 2; mi++)
#pragma unroll
      for (int ni = 0; ni < 8; ni++)
        accs[mi][ni] = __builtin_amdgcn_mfma_f32_16x16x32_bf16(a[mi], bb[ni], accs[mi][ni], 0, 0, 0);
  }

#pragma unroll
  for (int mi = 0; mi < 2; mi++) {
#pragma unroll
    for (int r = 0; r < 4; r++) {
      int wq = mi * 16 + kg * 4 + r;
      int q_e = q0 + wq;
      float v[8];
      float mx = -3.0e38f;
      int qp = 0; float qm = 1.f;
      if (has_mask) { qp = ph_sh[q_e]; qm = mk_sh[q_e]; }
#pragma unroll
      for (int ni = 0; ni < 8; ni++) {
        float s = accs[mi][ni][r] * 0.125f;
        if (has_mask) {
          int t_e = ni * 16 + r16;
          bool sib = (qp == ph_sh[t_e]) && (q_e != t_e) && (qm > 0.f) && (mk_sh[t_e] > 0.f);
          if (!sib) s = -1e9f;
        }
        v[ni] = s;
        mx = fmaxf(mx, s);
      }
#pragma unroll
      for (int o = 1; o < 16; o <<= 1) mx = fmaxf(mx, __shfl_xor(mx, o, 64));
      float sum = 0.f;
#pragma unroll
      for (int ni = 0; ni < 8; ni++) { v[ni] = __expf(v[ni] - mx); sum += v[ni]; }
#pragma unroll
      for (int o = 1; o < 16; o <<= 1) sum += __shfl_xor(sum, o, 64);
      float inv = 1.f / sum;
      int swz = (wq & 7) << 3;
#pragma unroll
      for (int ni = 0; ni < 8; ni++) {
        int t_e = ni * 16 + r16;
        P_lds[w][(wq * 128 + t_e) ^ swz] = f2b(v[ni] * inv);
      }
    }
  }
  __syncthreads();

  f32x4v acco[2][4];
#pragma unroll
  for (int mi = 0; mi < 2; mi++)
#pragma unroll
    for (int ni = 0; ni < 4; ni++) acco[mi][ni] = zero;

#pragma unroll
  for (int kt = 0; kt < 4; kt++) {
    int t = kt * 32 + kg * 8;
    bf16x8v a[2], bb[4];
#pragma unroll
    for (int mi = 0; mi < 2; mi++) {
      int wqr = mi * 16 + r16;
      int idx = (wqr * 128 + t) ^ ((wqr & 7) << 3);
      a[mi] = *(const bf16x8v*)&P_lds[w][idx];
    }
#pragma unroll
    for (int ni = 0; ni < 4; ni++)
      bb[ni] = *(const bf16x8v*)(Vh + (size_t)(ni * 16 + r16) * NN + t);
#pragma unroll
    for (int mi = 0; mi < 2; mi++)
#pragma unroll
      for (int ni = 0; ni < 4; ni++)
        acco[mi][ni] = __builtin_amdgcn_mfma_f32_16x16x32_bf16(a[mi], bb[ni], acco[mi][ni], 0, 0, 0);
  }

#pragma unroll
  for (int ni = 0; ni < 4; ni++) {
    int d = ni * 16 + r16;
#pragma unroll
    for (int mi = 0; mi < 2; mi++) {
      int qrow = q0 + mi * 16 + kg * 4;
      size_t base = ((size_t)b * NN + qrow) * DM + (size_t)h * HDIM + d;
#pragma unroll
      for (int r = 0; r < 4; r++)
        Ob[base + (size_t)r * DM] = f2b(acco[mi][ni][r]);
    }
  }
}

// ---------------------------------------------------------------------------
// child_avg v2 — unchanged (verified).
// ---------------------------------------------------------------------------
__global__ __launch_bounds__(256) void child_avg2_kernel(
    const bf16* __restrict__ Hr, const int* __restrict__ ph,
    const float* __restrict__ mask, bf16* __restrict__ CA)
{
  const int b = blockIdx.x;
  const int t = threadIdx.x;
  __shared__ int hi[NN];
  __shared__ float mk[NN];
  __shared__ int cnt[NN], off[NN], rnk[NN], lst[NN];
  __shared__ float cntf[NN];

  if (t < NN) {
    int g = ph[(size_t)b * NN + t];
    hi[t] = min(max(g, 0), NN - 1);
    mk[t] = mask[(size_t)b * NN + t];
  }
  __syncthreads();
  if (t < NN) {
    int c = 0, r = 0; float cf = 0.f;
    int me = hi[t];
    for (int j = 0; j < NN; j++) {
      int hj = hi[j];
      c  += (hj == t);
      cf += (hj == t) ? mk[j] : 0.f;
      r  += (j < t) && (hj == me);
    }
    cnt[t] = c; cntf[t] = cf; rnk[t] = r;
  }
  __syncthreads();
  if (t < NN) {
    int o = 0;
    for (int m = 0; m < t; m++) o += cnt[m];
    off[t] = o;
  }
  __syncthreads();
  if (t < NN) lst[off[hi[t]] + rnk[t]] = t;
  __syncthreads();

  const bf16* Hb = Hr + (size_t)b * NN * DM;
  bf16* Cb = CA + (size_t)b * NN * DM;
  const int d = t;
  for (int m = 0; m < NN; m++) {
    float s = 0.f;
    int o = off[m], c = cnt[m];
    for (int i = 0; i < c; i++)
      s += b2f(Hb[(size_t)lst[o + i] * DM + d]);
    Cb[(size_t)m * DM + d] = f2b(s / fmaxf(cntf[m], 1.f));
  }
}

// ---------------------------------------------------------------------------
// LN epilogue — unchanged (verified).
// ---------------------------------------------------------------------------
__global__ __launch_bounds__(256) void ln_epi_kernel(
    const bf16* __restrict__ Hr, const bf16* __restrict__ Gp, const bf16* __restrict__ Up,
    const float* __restrict__ lg, const float* __restrict__ lb, bf16* __restrict__ Hout)
{
  const int b = blockIdx.y;
  const int m0 = blockIdx.x * 8;
  const int c = threadIdx.x;
  __shared__ float red[8];
  float lgv = lg[c], lbv = lb[c];
  int wv = c >> 6, ln = c & 63;
  for (int m = 0; m < 8; m++) {
    size_t idx = ((size_t)b * NN + m0 + m) * DM + c;
    float g = 1.f / (1.f + __expf(-b2f(Gp[idx])));
    float u = geluf(b2f(Up[idx]));
    float hn = b2f(Hr[idx]) + g * u;
    float s1 = hn, s2 = hn * hn;
#pragma unroll
    for (int o = 1; o < 64; o <<= 1) { s1 += __shfl_xor(s1, o, 64); s2 += __shfl_xor(s2, o, 64); }
    if (ln == 0) { red[wv] = s1; red[4 + wv] = s2; }
    __syncthreads();
    float sum = red[0] + red[1] + red[2] + red[3];
    float sq  = red[4] + red[5] + red[6] + red[7];
    float mu = sum * (1.f / DM);
    float var = sq * (1.f / DM) - mu * mu;
    float y = (hn - mu) * rsqrtf(var + 1e-5f) * lgv + lbv;
    Hout[idx] = f2b(y);
    __syncthreads();
  }
}

// rh from Hr via folded vector; rd from h_dep.
__global__ __launch_bounds__(256) void rhrd2_kernel(
    const bf16* __restrict__ Hc, const bf16* __restrict__ hd,
    const float* __restrict__ vha, const float* __restrict__ cha,
    const float* __restrict__ bdw, const float* __restrict__ bdb,
    float* __restrict__ rh, float* __restrict__ rd)
{
  int b = blockIdx.x;
  int t = threadIdx.x;
  int n = t & 127;
  bool isD = t >= 128;
  if (!isD) {
    const bf16* row = Hc + ((size_t)b * NN + n) * DM;
    float s = cha[0];
    for (int k = 0; k < DM; k++) s += b2f(row[k]) * vha[k];
    rh[(size_t)b * NN + n] = s;
  } else {
    const bf16* row = hd + ((size_t)b * NN + n) * DM;
    float s = bdb[0];
    for (int k = 0; k < DM; k++) s += b2f(row[k]) * bdw[k];
    rd[(size_t)b * NN + n] = s;
  }
}

// scores — r8-verified.
__global__ __launch_bounds__(512) void scores_mfma_kernel(
    const bf16* __restrict__ tmp, const bf16* __restrict__ hd,
    const float* __restrict__ rh, const float* __restrict__ rd,
    float* __restrict__ out)
{
  const int b = blockIdx.x;
  const int w = threadIdx.x >> 6;
  const int lane = threadIdx.x & 63;
  const int wr = w >> 1, wc = w & 1;
  const int r16 = lane & 15;
  const int kg = lane >> 4;

  size_t qoff[2], moff[4];
#pragma unroll
  for (int mi = 0; mi < 2; mi++) qoff[mi] = ((size_t)b * NN + wr * 32 + mi * 16 + r16) * DM;
#pragma unroll
  for (int ni = 0; ni < 4; ni++) moff[ni] = ((size_t)b * NN + wc * 64 + ni * 16 + r16) * DM;

  f32x4v zero = {0.f, 0.f, 0.f, 0.f};
  f32x4v acc[2][4];
#pragma unroll
  for (int mi = 0; mi < 2; mi++)
#pragma unroll
    for (int ni = 0; ni < 4; ni++) acc[mi][ni] = zero;

  for (int k0 = 0; k0 < DM; k0 += 32) {
    int k = k0 + kg * 8;
    bf16x8v a[2], bb[4];
#pragma unroll
    for (int mi = 0; mi < 2; mi++) a[mi] = *(const bf16x8v*)(tmp + qoff[mi] + k);
#pragma unroll
    for (int ni = 0; ni < 4; ni++) bb[ni] = *(const bf16x8v*)(hd + moff[ni] + k);
#pragma unroll
    for (int mi = 0; mi < 2; mi++)
#pragma unroll
      for (int ni = 0; ni < 4; ni++)
        acc[mi][ni] = __builtin_amdgcn_mfma_f32_16x16x32_bf16(a[mi], bb[ni], acc[mi][ni], 0, 0, 0);
  }

#pragma unroll
  for (int ni = 0; ni < 4; ni++) {
    int m = wc * 64 + ni * 16 + r16;
    float rhm = rh[b * NN + m];
#pragma unroll
    for (int mi = 0; mi < 2; mi++) {
      int q0 = wr * 32 + mi * 16 + kg * 4;
#pragma unroll
      for (int r = 0; r < 4; r++)
        out[(size_t)b * NN * NN + (size_t)(q0 + r) * NN + m] =
            acc[mi][ni][r] + rhm + rd[b * NN + q0 + r];
    }
  }
}

// ---------------------------------------------------------------------------
extern "C" void kernel_launch(void* const* d_in, const int* in_sizes, int n_in,
                              void* d_out, int out_size, void* d_ws, size_t ws_size,
                              hipStream_t stream) {
  const float* H      = (const float*)d_in[0];
  const int*   ph     = (const int*)  d_in[1];
  const float* mask   = (const float*)d_in[2];
  const float* ha_w   = (const float*)d_in[3];
  const float* ha_b   = (const float*)d_in[4];
  const float* sa_w   = (const float*)d_in[5];
  const float* sa_b   = (const float*)d_in[6];
  const float* ct_w   = (const float*)d_in[7];
  const float* ct_b   = (const float*)d_in[8];
  const float* gate_w = (const float*)d_in[9];
  const float* gate_b = (const float*)d_in[10];
  const float* tr_w   = (const float*)d_in[11];
  const float* tr_b   = (const float*)d_in[12];
  const float* ln_g   = (const float*)d_in[13];
  const float* ln_b   = (const float*)d_in[14];
  const float* ahw    = (const float*)d_in[15];
  const float* ahb    = (const float*)d_in[16];
  const float* adw    = (const float*)d_in[17];
  const float* adb    = (const float*)d_in[18];
  const float* bil    = (const float*)d_in[19];
  const float* bhw    = (const float*)d_in[20];
  const float* bhb    = (const float*)d_in[21];
  const float* bdw    = (const float*)d_in[22];
  const float* bdb    = (const float*)d_in[23];

  const size_t AB = (size_t)BD * NN * DM;  // 8,388,608 elems
  bf16* wsb  = (bf16*)d_ws;
  bf16* Hcur = wsb + 0 * AB;
  bf16* Qa   = wsb + 1 * AB;
  bf16* Ka   = wsb + 2 * AB;   // final: h_dep
  bf16* Va   = wsb + 3 * AB;   // V^T (ha); later Gpre; final: U
  bf16* Qs   = wsb + 4 * AB;
  bf16* Ks   = wsb + 5 * AB;
  bf16* Vs   = wsb + 6 * AB;   // V^T (sa); later Upre
  bf16* mC   = wsb + 7 * AB;
  float* rh  = (float*)(wsb + 8 * AB);
  float* rd  = rh + (size_t)BD * NN;
  float* fgb = rd + (size_t)BD * NN;       // [3][256]
  float* ftb = fgb + 768;                  // [3][256]
  float* fab_bias = ftb + 768;             // [256]
  float* vha = fab_bias + 256;             // [256]
  float* cha = vha + 256;                  // [1]

  // d_out doubles as scratch: 3 regions of AB bf16 each.
  bf16* D0 = (bf16*)d_out;            // CA, then Oa; overwritten by final cvt
  bf16* D1 = D0 + AB;                 // Os; overwritten by final cvt
  bf16* D2 = D0 + 2 * AB;             // weight arena; overwritten by scores
  const size_t RS = 1179648;          // per-round arena stride (bf16 units)
  bf16* adT  = D2 + 3 * RS;           // 65536
  bf16* fabT = adT + 65536;           // 65536

  cvt32to16_kernel<<<dim3(2048), 256, 0, stream>>>(H, Hcur, (int)AB);

  // ---- prologue: all weight transposes + fuses (data-independent) ----
  for (int r = 0; r < RR; r++) {
    bf16* base_r = D2 + (size_t)r * RS;
    bf16* haT = base_r;
    bf16* saT = base_r + 262144;
    bf16* ctT = base_r + 524288;
    bf16* gT  = base_r + 655360;
    bf16* tT  = base_r + 917504;
    TTable T; int base = 0;
    for (int i = 0; i < 3; i++) {
      T.e[i] = { ha_w + ((size_t)r * 4 + i) * 65536, haT + (size_t)i * 65536, 256, base };
      base += 64;
    }
    for (int i = 0; i < 3; i++) {
      T.e[3 + i] = { sa_w + ((size_t)r * 4 + i) * 65536, saT + (size_t)i * 65536, 256, base };
      base += 64;
    }
    T.e[6] = { ct_w + (size_t)r * 131072, ctT, 512, base };                    base += 128;
    T.e[7] = { gate_w + (size_t)r * 262144,             gT,        1024, base }; base += 64;
    T.e[8] = { gate_w + (size_t)r * 262144 + 512 * 256, gT + 512,  1024, base }; base += 64;
    T.e[9] = { tr_w   + (size_t)r * 262144,             tT,        1024, base }; base += 64;
    T.e[10]= { tr_w   + (size_t)r * 262144 + 512 * 256, tT + 512,  1024, base }; base += 64;
    int nent = 11;
    if (r == 0) { T.e[11] = { adw, adT, 256, base }; base += 64; nent = 12; }
    transpose_w_kernel<<<dim3(base), 256, 0, stream>>>(T, nent);
  }
  {
    FJobs F;
    for (int r = 0; r < RR; r++) {
      bf16* gT = D2 + (size_t)r * RS + 655360;
      bf16* tT = D2 + (size_t)r * RS + 917504;
      const float* WoH = ha_w + ((size_t)r * 4 + 3) * 65536;
      const float* WoS = sa_w + ((size_t)r * 4 + 3) * 65536;
      const float* gw = gate_w + (size_t)r * 262144;
      const float* tw = tr_w   + (size_t)r * 262144;
      F.j[r * 4 + 0] = { WoH, gw + 256 * 256, gT, 256, 1024 };
      F.j[r * 4 + 1] = { WoS, gw + 768 * 256, gT, 768, 1024 };
      F.j[r * 4 + 2] = { WoH, tw + 256 * 256, tT, 256, 1024 };
      F.j[r * 4 + 3] = { WoS, tw + 768 * 256, tT, 768, 1024 };
    }
    F.j[12] = { ahw, bil, fabT, 0, 256 };
    wfuse_kernel<<<dim3(16, 13), 256, 0, stream>>>(F);
  }
  bfuse_kernel<<<dim3(7), 256, 0, stream>>>(gate_w, tr_w, gate_b, tr_b,
      ha_b, sa_b, ahw, ahb, bil, bhw, bhb, fgb, ftb, fab_bias, vha, cha);

  // ---- rounds ----
  for (int r = 0; r < RR; r++) {
    bf16* base_r = D2 + (size_t)r * RS;
    bf16* haT = base_r;
    bf16* saT = base_r + 262144;
    bf16* ctT = base_r + 524288;
    bf16* gT  = base_r + 655360;
    bf16* tT  = base_r + 917504;
    const float* hab = ha_b + (size_t)r * 4 * DM;
    const float* sab = sa_b + (size_t)r * 4 * DM;

    child_avg2_kernel<<<dim3(BD), 256, 0, stream>>>(Hcur, ph, mask, D0);

    {
      ProjArgs P;
      P.Hc = Hcur; P.CA = D0; P.gather = ph;
      P.W[0] = haT;          P.bias[0] = hab + 0;   P.out[0] = Qa;
      P.W[1] = haT + 65536;  P.bias[1] = hab + 256; P.out[1] = Ka;
      P.W[2] = haT + 131072; P.bias[2] = hab + 512; P.out[2] = Va;
      P.W[3] = saT;          P.bias[3] = sab + 0;   P.out[3] = Qs;
      P.W[4] = saT + 65536;  P.bias[4] = sab + 256; P.out[4] = Ks;
      P.W[5] = saT + 131072; P.bias[5] = sab + 512; P.out[5] = Vs;
      P.W[6] = ctT;          P.bias[6] = ct_b + (size_t)r * DM; P.out[6] = mC;
      proj_fused_kernel<<<dim3(512), 256, 0, stream>>>(P);
    }

    {
      AttnArgs A = { Qa, Ka, Va, D0, Qs, Ks, Vs, D1 };
      attn2_kernel<<<dim3(NHD, BD, 2), 256, 0, stream>>>(A, ph, mask);
    }

    // gate + tr with folded O-projections, ONE dual dispatch
    {
      DJob J = { Hcur, D0, mC, D1, gT, tT,
                 fgb + (size_t)r * 256, ftb + (size_t)r * 256, Va, Vs, 1024 };
      dualw_gemm_kernel<<<dim3(512), 512, 0, stream>>>(J);
    }

    ln_epi_kernel<<<dim3(16, BD), 256, 0, stream>>>(Hcur, Va, Vs,
        ln_g + (size_t)r * DM, ln_b + (size_t)r * DM, Hcur);
  }

  // ---- final biaffine scorer (h_head folded away), ONE dual dispatch ----
  {
    DJob J = { Hcur, Hcur, Hcur, Hcur, adT, fabT, adb, fab_bias, Ka, Va, 256 };
    dualw_gemm_kernel<<<dim3(512), 512, 0, stream>>>(J);
  }
  rhrd2_kernel<<<dim3(BD), 256, 0, stream>>>(Hcur, Ka, vha, cha, bdw, bdb, rh, rd);
  scores_mfma_kernel<<<dim3(BD), 512, 0, stream>>>(Va, Ka, rh, rd, (float*)d_out + AB);

  cvt16to32_kernel<<<dim3(2048), 256, 0, stream>>>(Hcur, (float*)d_out, (int)AB);
}

// Round 18
// 935.349 us; speedup vs baseline: 1.1063x; 1.1063x over previous
//
#include <hip/hip_runtime.h>
#include <hip/hip_bf16.h>
#include <math.h>

typedef __hip_bfloat16 bf16;
typedef __attribute__((ext_vector_type(8))) short bf16x8v;
typedef __attribute__((ext_vector_type(4))) float f32x4v;

#define BD 256   // batch
#define NN 128   // tokens
#define DM 256   // model dim
#define NHD 4    // heads
#define HDIM 64  // head dim
#define RR 3     // rounds

__device__ __forceinline__ float b2f(bf16 x) { return __bfloat162float(x); }
__device__ __forceinline__ bf16 f2b(float x) { return __float2bfloat16(x); }
__device__ __forceinline__ float geluf(float x) { return 0.5f * x * (1.f + erff(x * 0.70710678118654752f)); }

#define GLOAD16(g, l) __builtin_amdgcn_global_load_lds( \
    (const __attribute__((address_space(1))) void*)(g), \
    (__attribute__((address_space(3))) void*)(l), 16, 0, 0)

// fp32 -> bf16 convert
__global__ __launch_bounds__(256) void cvt32to16_kernel(
    const float* __restrict__ in, bf16* __restrict__ out, int n)
{
  int i = blockIdx.x * 256 + threadIdx.x;
  int stride = gridDim.x * 256;
  for (; i < n; i += stride) out[i] = f2b(in[i]);
}

// bf16 -> fp32
__global__ __launch_bounds__(256) void cvt16to32_kernel(
    const bf16* __restrict__ in, float* __restrict__ out, int n)
{
  int i = blockIdx.x * 256 + threadIdx.x;
  int stride = gridDim.x * 256;
  for (; i < n; i += stride) out[i] = b2f(in[i]);
}

// ---------------------------------------------------------------------------
// Batched weight transpose: src fp32 [*][256] row-major -> dst bf16 [256][K].
// ---------------------------------------------------------------------------
struct TDesc { const float* src; bf16* dst; int K; int base; };
struct TTable { TDesc e[12]; };

__global__ __launch_bounds__(256) void transpose_w_kernel(TTable T, int nent)
{
  int t = blockIdx.x;
  int ei = 0;
  for (int i = 1; i < nent; i++) if (t >= T.e[i].base) ei = i;
  const float* src = T.e[ei].src;
  bf16* dst = T.e[ei].dst;
  int K = T.e[ei].K;
  int lt = t - T.e[ei].base;
  int nt = lt & 7, kt = lt >> 3;

  __shared__ float tile[32][33];
  int tx = threadIdx.x & 31, ty = threadIdx.x >> 5;
#pragma unroll
  for (int i = 0; i < 4; i++)
    tile[ty + i * 8][tx] = src[(size_t)(kt * 32 + ty + i * 8) * 256 + nt * 32 + tx];
  __syncthreads();
#pragma unroll
  for (int i = 0; i < 4; i++)
    dst[(size_t)(nt * 32 + ty + i * 8) * K + kt * 32 + tx] = f2b(tile[tx][ty + i * 8]);
}

// ---------------------------------------------------------------------------
// Weight-fuse: outT[col][koff+k] = f2b( sum_m A[k][m] * B[m][col] ), 256x256.
// ---------------------------------------------------------------------------
struct FJob { const float* A; const float* B; bf16* outT; int koff; int kst; };
struct FJobs { FJob j[13]; };

__global__ __launch_bounds__(256) void wfuse_kernel(FJobs F)
{
  const FJob jb = F.j[blockIdx.y];
  const int k0 = blockIdx.x * 16;
  const int col = threadIdx.x;
  float acc[16];
#pragma unroll
  for (int i = 0; i < 16; i++) acc[i] = 0.f;
  for (int m = 0; m < 256; m++) {
    float bv = jb.B[(size_t)m * 256 + col];
#pragma unroll
    for (int i = 0; i < 16; i++)
      acc[i] += jb.A[(size_t)(k0 + i) * 256 + m] * bv;
  }
#pragma unroll
  for (int i = 0; i < 16; i++)
    jb.outT[(size_t)col * jb.kst + jb.koff + k0 + i] = f2b(acc[i]);
}

// ---------------------------------------------------------------------------
// Bias-fuse: blocks 0..5 -> fgb/ftb per round; block 6 -> fab_bias, vha, cha.
// ---------------------------------------------------------------------------
__global__ __launch_bounds__(256) void bfuse_kernel(
    const float* gate_w, const float* tr_w, const float* gate_b, const float* tr_b,
    const float* ha_b, const float* sa_b,
    const float* ahw, const float* ahb, const float* bil,
    const float* bhw, const float* bhb,
    float* fgb, float* ftb, float* fab_bias, float* vha, float* cha)
{
  int blk = blockIdx.x, col = threadIdx.x;
  if (blk < 6) {
    int r = blk >> 1; bool isT = blk & 1;
    const float* W  = (isT ? tr_w : gate_w) + (size_t)r * 262144;
    const float* b0 = (isT ? tr_b : gate_b) + (size_t)r * 256;
    const float* boh = ha_b + (size_t)r * 1024 + 768;
    const float* bos = sa_b + (size_t)r * 1024 + 768;
    float acc = b0[col];
    for (int m = 0; m < 256; m++) {
      acc += boh[m] * W[(size_t)(256 + m) * 256 + col];
      acc += bos[m] * W[(size_t)(768 + m) * 256 + col];
    }
    ((isT ? ftb : fgb) + (size_t)r * 256)[col] = acc;
  } else {
    float a1 = 0.f, a2 = 0.f;
    for (int m = 0; m < 256; m++) {
      a1 += ahb[m] * bil[(size_t)m * 256 + col];
      a2 += ahw[(size_t)col * 256 + m] * bhw[m];
    }
    fab_bias[col] = a1;
    vha[col] = a2;
    if (col == 0) {
      float c = bhb[0];
      for (int m = 0; m < 256; m++) c += ahb[m] * bhw[m];
      cha[0] = c;
    }
  }
}

// ---------------------------------------------------------------------------
// proj_fused (r13 champion): 7 GEMMs share A (Hcur) in LDS; W dbuf in LDS.
// grid (512) = (b, colhalf). Block 256 = 4 waves, wave tile 64x64.
// LDS: A full-K [128][256] bf16 = 64KB @0 (slot-swizzled), W dbuf 2x8KB @65536.
// jobs: 0 haQ, 1 haK(g), 2 haV(g,tr), 3 saQ, 4 saK, 5 saV(tr), 6 ct(gelu).
// ---------------------------------------------------------------------------
struct ProjArgs {
  const bf16* Hc; const bf16* CA; const int* gather;
  const bf16* W[7];
  const float* bias[7];
  bf16* out[7];
};

__global__ __launch_bounds__(256) void proj_fused_kernel(ProjArgs P)
{
  const int b  = blockIdx.x & 255;
  const int nh = blockIdx.x >> 8;
  const int c0 = nh * 128;
  const int tid = threadIdx.x;
  const int w = tid >> 6;
  const int lane = tid & 63;
  const int wr = w >> 1, wc = w & 1;
  const int r16 = lane & 15;
  const int kg = lane >> 4;

  __shared__ __align__(16) char lds[81920];

  const char* Hb = (const char*)(P.Hc + (size_t)b * NN * DM);

#pragma unroll
  for (int i = 0; i < 16; i++) {
    int row = w * 32 + i * 2 + (lane >> 5);
    int src = row * 512 + (((lane & 31) * 16) ^ ((row & 7) << 4));
    GLOAD16(Hb + src, lds + w * 16384 + i * 1024);
  }

#define STAGE_W(WT, K2, KT, BUF) do { \
    _Pragma("unroll") \
    for (int i_ = 0; i_ < 2; i_++) { \
      int wrow_ = w * 32 + i_ * 16 + (lane >> 2); \
      int slot_ = (lane & 3) ^ ((wrow_ >> 1) & 3); \
      GLOAD16((const char*)(WT) + (size_t)(c0 + wrow_) * (K2) + (KT) * 64 + slot_ * 16, \
              lds + 65536 + (BUF) * 8192 + w * 2048 + i_ * 1024); \
    } } while (0)

  STAGE_W(P.W[0], 512, 0, 0);
  __syncthreads();

  int lrow[4], grow[4];
#pragma unroll
  for (int mi = 0; mi < 4; mi++) {
    lrow[mi] = wr * 64 + mi * 16 + r16;
    int g = P.gather[b * NN + lrow[mi]];
    grow[mi] = min(max(g, 0), NN - 1);
  }
  int wro[4];
#pragma unroll
  for (int ni = 0; ni < 4; ni++) {
    int ct_ = wc * 64 + ni * 16 + r16;
    wro[ni] = ct_ * 64 + ((kg ^ ((ct_ >> 1) & 3)) << 4);
  }

  const bf16* CAb = P.CA + (size_t)b * NN * DM;
  int buf = 0;
  f32x4v zero = {0.f, 0.f, 0.f, 0.f};

#pragma unroll
  for (int j = 0; j < 7; j++) {
    const bool GATH = (j == 1) || (j == 2);
    const bool TR   = (j == 2) || (j == 5);
    const bool ACT  = (j == 6);
    const int NKS = (j == 6) ? 16 : 8;
    const int K2  = (j == 6) ? 1024 : 512;
    const bf16* Wj  = P.W[j];
    const bf16* Wj1 = (j < 6) ? P.W[j + 1] : P.W[j];
    const int  K2n  = (j < 6) ? ((j + 1 == 6) ? 1024 : 512) : K2;

    f32x4v acc[4][4];
#pragma unroll
    for (int mi = 0; mi < 4; mi++)
#pragma unroll
      for (int ni = 0; ni < 4; ni++) acc[mi][ni] = zero;

    for (int kt = 0; kt < NKS; kt++) {
      if (!(j == 6 && kt + 1 == NKS)) {
        const bf16* Wn = (kt + 1 < NKS) ? Wj : Wj1;
        int nkt = (kt + 1 < NKS) ? kt + 1 : 0;
        int nK2 = (kt + 1 < NKS) ? K2 : K2n;
        STAGE_W(Wn, nK2, nkt, buf ^ 1);
      }

      bf16x8v a[4], wv[4];
      if (j == 6 && kt >= 8) {
#pragma unroll
        for (int mi = 0; mi < 4; mi++)
          a[mi] = *(const bf16x8v*)(CAb + (size_t)lrow[mi] * DM + (kt - 8) * 32 + kg * 8);
      } else {
#pragma unroll
        for (int mi = 0; mi < 4; mi++) {
          int ar = GATH ? grow[mi] : lrow[mi];
          int off = ar * 512 + (((kt * 64) + kg * 16) ^ ((ar & 7) << 4));
          a[mi] = *(const bf16x8v*)(lds + off);
        }
      }
#pragma unroll
      for (int ni = 0; ni < 4; ni++)
        wv[ni] = *(const bf16x8v*)(lds + 65536 + buf * 8192 + wro[ni]);

#pragma unroll
      for (int mi = 0; mi < 4; mi++)
#pragma unroll
        for (int ni = 0; ni < 4; ni++)
          acc[mi][ni] = __builtin_amdgcn_mfma_f32_16x16x32_bf16(a[mi], wv[ni], acc[mi][ni], 0, 0, 0);

      __syncthreads();
      buf ^= 1;
    }

    bf16* outj = P.out[j];
    const float* bj = P.bias[j];
#pragma unroll
    for (int ni = 0; ni < 4; ni++) {
      int col = c0 + wc * 64 + ni * 16 + r16;
      float bv = bj ? bj[col] : 0.f;
#pragma unroll
      for (int mi = 0; mi < 4; mi++) {
        int row0 = wr * 64 + mi * 16 + kg * 4;
        if (!TR) {
          size_t base = ((size_t)b * NN + row0) * DM + col;
#pragma unroll
          for (int r = 0; r < 4; r++) {
            float x = acc[mi][ni][r] + bv;
            if (ACT) x = geluf(x);
            outj[base + (size_t)r * DM] = f2b(x);
          }
        } else {
          size_t base = ((size_t)b * DM + col) * NN + row0;
#pragma unroll
          for (int r = 0; r < 4; r++)
            outj[base + r] = f2b(acc[mi][ni][r] + bv);
        }
      }
    }
  }
#undef STAGE_W
}

// ---------------------------------------------------------------------------
// dualw_gemm: TWO GEMMs sharing A (r13-verified). 8 waves: 0-3 -> W0, 4-7 -> W1.
// ---------------------------------------------------------------------------
struct DJob {
  const bf16 *a0, *a1, *a2, *a3;
  const bf16 *W0, *W1;
  const float *b0, *b1;
  bf16 *o0, *o1;
  int K;
};

__global__ __launch_bounds__(512) void dualw_gemm_kernel(DJob jb)
{
  const int b  = blockIdx.x & 255;
  const int nh = blockIdx.x >> 8;
  const int c0 = nh * 128;
  const int tid = threadIdx.x;
  const int w = tid >> 6;
  const int jj = w >> 2;
  const int wsub = w & 3;
  const int wr = wsub >> 1, wc = wsub & 1;
  const int lane = tid & 63;
  const int r16 = lane & 15;
  const int kg = lane >> 4;
  const int K = jb.K;
  const int nk = K >> 5;

  __shared__ __align__(16) char lds[49152];

  const int srow = tid >> 2;
  const int skc  = tid & 3;
  const int sl   = skc ^ ((srow >> 1) & 3);
  const size_t aoff = ((size_t)b * NN + srow) * DM + sl * 8;
  const bf16* w0src = jb.W0 + (size_t)(c0 + srow) * K + sl * 8;
  const bf16* w1src = jb.W1 + (size_t)(c0 + srow) * K + sl * 8;
  const int wbase = w * 1024;

  f32x4v zero = {0.f, 0.f, 0.f, 0.f};
  f32x4v acc[4][4];
#pragma unroll
  for (int mi = 0; mi < 4; mi++)
#pragma unroll
    for (int ni = 0; ni < 4; ni++) acc[mi][ni] = zero;

  int a_ro[4], w_ro[4];
#pragma unroll
  for (int mi = 0; mi < 4; mi++) {
    int row = wr * 64 + mi * 16 + r16;
    a_ro[mi] = row * 64 + ((kg ^ ((row >> 1) & 3)) << 4);
  }
  const int wsel = 16384 + jj * 16384;
#pragma unroll
  for (int ni = 0; ni < 4; ni++) {
    int col = wc * 64 + ni * 16 + r16;
    w_ro[ni] = col * 64 + ((kg ^ ((col >> 1) & 3)) << 4);
  }

  {
    GLOAD16(jb.a0 + aoff, lds + wbase);
    GLOAD16(w0src,        lds + 16384 + wbase);
    GLOAD16(w1src,        lds + 32768 + wbase);
  }
  __syncthreads();

  int cur = 0;
  for (int kt = 0; kt < nk; kt++) {
    if (kt + 1 < nk) {
      int k0 = (kt + 1) << 5;
      int sg = k0 >> 8;
      const bf16* Ab = (sg == 0) ? jb.a0 : ((sg == 1) ? jb.a1 : ((sg == 2) ? jb.a2 : jb.a3));
      int ko = k0 & 255;
      int nb = (cur ^ 1) * 8192;
      GLOAD16(Ab + aoff + ko,  lds + nb + wbase);
      GLOAD16(w0src + k0,      lds + 16384 + nb + wbase);
      GLOAD16(w1src + k0,      lds + 32768 + nb + wbase);
    }

    const char* La = lds + cur * 8192;
    const char* Lw = lds + wsel + cur * 8192;
    bf16x8v a[4], ww[4];
#pragma unroll
    for (int mi = 0; mi < 4; mi++) a[mi] = *(const bf16x8v*)(La + a_ro[mi]);
#pragma unroll
    for (int ni = 0; ni < 4; ni++) ww[ni] = *(const bf16x8v*)(Lw + w_ro[ni]);
#pragma unroll
    for (int mi = 0; mi < 4; mi++)
#pragma unroll
      for (int ni = 0; ni < 4; ni++)
        acc[mi][ni] = __builtin_amdgcn_mfma_f32_16x16x32_bf16(a[mi], ww[ni], acc[mi][ni], 0, 0, 0);

    __syncthreads();
    cur ^= 1;
  }

  bf16* out = jj ? jb.o1 : jb.o0;
  const float* bias = jj ? jb.b1 : jb.b0;
#pragma unroll
  for (int ni = 0; ni < 4; ni++) {
    int col = c0 + wc * 64 + ni * 16 + r16;
    float bv = bias ? bias[col] : 0.f;
#pragma unroll
    for (int mi = 0; mi < 4; mi++) {
      int row0 = wr * 64 + mi * 16 + kg * 4;
      size_t base = ((size_t)b * NN + row0) * DM + col;
#pragma unroll
      for (int r = 0; r < 4; r++)
        out[base + (size_t)r * DM] = f2b(acc[mi][ni][r] + bv);
    }
  }
}

// ---------------------------------------------------------------------------
// Fused dual MFMA attention — r8-verified.
// ---------------------------------------------------------------------------
struct AttnArgs {
  const bf16 *Qa, *Ka, *Va; bf16* Oa;
  const bf16 *Qs, *Ks, *Vs; bf16* Os;
};

__global__ __launch_bounds__(256) void attn2_kernel(
    AttnArgs A, const int* __restrict__ ph, const float* __restrict__ mask)
{
  const int b = blockIdx.y, h = blockIdx.x;
  const bool has_mask = (blockIdx.z == 1);
  const bf16* Qb = has_mask ? A.Qs : A.Qa;
  const bf16* Kb = has_mask ? A.Ks : A.Ka;
  const bf16* Vt = has_mask ? A.Vs : A.Va;
  bf16* Ob       = has_mask ? A.Os : A.Oa;

  const int w = threadIdx.x >> 6;
  const int lane = threadIdx.x & 63;
  const int r16 = lane & 15, kg = lane >> 4;
  const int q0 = w * 32;

  __shared__ bf16 P_lds[4][32 * 128];
  __shared__ int   ph_sh[NN];
  __shared__ float mk_sh[NN];

  if (has_mask && threadIdx.x < NN) {
    ph_sh[threadIdx.x] = ph[(size_t)b * NN + threadIdx.x];
    mk_sh[threadIdx.x] = mask[(size_t)b * NN + threadIdx.x];
  }
  __syncthreads();

  const bf16* Qh = Qb + (size_t)b * NN * DM + (size_t)h * HDIM;
  const bf16* Kh = Kb + (size_t)b * NN * DM + (size_t)h * HDIM;
  const bf16* Vh = Vt + ((size_t)b * DM + (size_t)h * HDIM) * NN;

  f32x4v zero = {0.f, 0.f, 0.f, 0.f};

  f32x4v accs[2][8];
#pragma unroll
  for (int mi = 0; mi < 2; mi++)
#pragma unroll
    for (int ni = 0; ni < 8; ni++) accs[mi][ni] = zero;

#pragma unroll
  for (int ks = 0; ks < 2; ks++) {
    int d = ks * 32 + kg * 8;
    bf16x8v a[2], bb[8];
#pragma unroll
    for (int mi = 0; mi < 2; mi++)
      a[mi] = *(const bf16x8v*)(Qh + (size_t)(q0 + mi * 16 + r16) * DM + d);
#pragma unroll
    for (int ni = 0; ni < 8; ni++)
      bb[ni] = *(const bf16x8v*)(Kh + (size_t)(ni * 16 + r16) * DM + d);
#pragma unroll
    for (int mi = 0; mi < 2; mi++)
#pragma unroll
      for (int ni = 0; ni < 8; ni++)
        accs[mi][ni] = __builtin_amdgcn_mfma_f32_16x16x32_bf16(a[mi], bb[ni], accs[mi][ni], 0, 0, 0);
  }

#pragma unroll
  for (int mi = 0; mi < 2; mi++) {
#pragma unroll
    for (int r = 0; r < 4; r++) {
      int wq = mi * 16 + kg * 4 + r;
      int q_e = q0 + wq;
      float v[8];
      float mx = -3.0e38f;
      int qp = 0; float qm = 1.f;
      if (has_mask) { qp = ph_sh[q_e]; qm = mk_sh[q_e]; }
#pragma unroll
      for (int ni = 0; ni < 8; ni++) {
        float s = accs[mi][ni][r] * 0.125f;
        if (has_mask) {
          int t_e = ni * 16 + r16;
          bool sib = (qp == ph_sh[t_e]) && (q_e != t_e) && (qm > 0.f) && (mk_sh[t_e] > 0.f);
          if (!sib) s = -1e9f;
        }
        v[ni] = s;
        mx = fmaxf(mx, s);
      }
#pragma unroll
      for (int o = 1; o < 16; o <<= 1) mx = fmaxf(mx, __shfl_xor(mx, o, 64));
      float sum = 0.f;
#pragma unroll
      for (int ni = 0; ni < 8; ni++) { v[ni] = __expf(v[ni] - mx); sum += v[ni]; }
#pragma unroll
      for (int o = 1; o < 16; o <<= 1) sum += __shfl_xor(sum, o, 64);
      float inv = 1.f / sum;
      int swz = (wq & 7) << 3;
#pragma unroll
      for (int ni = 0; ni < 8; ni++) {
        int t_e = ni * 16 + r16;
        P_lds[w][(wq * 128 + t_e) ^ swz] = f2b(v[ni] * inv);
      }
    }
  }
  __syncthreads();

  f32x4v acco[2][4];
#pragma unroll
  for (int mi = 0; mi < 2; mi++)
#pragma unroll
    for (int ni = 0; ni < 4; ni++) acco[mi][ni] = zero;

#pragma unroll
  for (int kt = 0; kt < 4; kt++) {
    int t = kt * 32 + kg * 8;
    bf16x8v a[2], bb[4];
#pragma unroll
    for (int mi = 0; mi < 2; mi++) {
      int wqr = mi * 16 + r16;
      int idx = (wqr * 128 + t) ^ ((wqr & 7) << 3);
      a[mi] = *(const bf16x8v*)&P_lds[w][idx];
    }
#pragma unroll
    for (int ni = 0; ni < 4; ni++)
      bb[ni] = *(const bf16x8v*)(Vh + (size_t)(ni * 16 + r16) * NN + t);
#pragma unroll
    for (int mi = 0; mi < 2; mi++)
#pragma unroll
      for (int ni = 0; ni < 4; ni++)
        acco[mi][ni] = __builtin_amdgcn_mfma_f32_16x16x32_bf16(a[mi], bb[ni], acco[mi][ni], 0, 0, 0);
  }

#pragma unroll
  for (int ni = 0; ni < 4; ni++) {
    int d = ni * 16 + r16;
#pragma unroll
    for (int mi = 0; mi < 2; mi++) {
      int qrow = q0 + mi * 16 + kg * 4;
      size_t base = ((size_t)b * NN + qrow) * DM + (size_t)h * HDIM + d;
#pragma unroll
      for (int r = 0; r < 4; r++)
        Ob[base + (size_t)r * DM] = f2b(acco[mi][ni][r]);
    }
  }
}

// ---------------------------------------------------------------------------
// child_avg v2 — unchanged (verified).
// ---------------------------------------------------------------------------
__global__ __launch_bounds__(256) void child_avg2_kernel(
    const bf16* __restrict__ Hr, const int* __restrict__ ph,
    const float* __restrict__ mask, bf16* __restrict__ CA)
{
  const int b = blockIdx.x;
  const int t = threadIdx.x;
  __shared__ int hi[NN];
  __shared__ float mk[NN];
  __shared__ int cnt[NN], off[NN], rnk[NN], lst[NN];
  __shared__ float cntf[NN];

  if (t < NN) {
    int g = ph[(size_t)b * NN + t];
    hi[t] = min(max(g, 0), NN - 1);
    mk[t] = mask[(size_t)b * NN + t];
  }
  __syncthreads();
  if (t < NN) {
    int c = 0, r = 0; float cf = 0.f;
    int me = hi[t];
    for (int j = 0; j < NN; j++) {
      int hj = hi[j];
      c  += (hj == t);
      cf += (hj == t) ? mk[j] : 0.f;
      r  += (j < t) && (hj == me);
    }
    cnt[t] = c; cntf[t] = cf; rnk[t] = r;
  }
  __syncthreads();
  if (t < NN) {
    int o = 0;
    for (int m = 0; m < t; m++) o += cnt[m];
    off[t] = o;
  }
  __syncthreads();
  if (t < NN) lst[off[hi[t]] + rnk[t]] = t;
  __syncthreads();

  const bf16* Hb = Hr + (size_t)b * NN * DM;
  bf16* Cb = CA + (size_t)b * NN * DM;
  const int d = t;
  for (int m = 0; m < NN; m++) {
    float s = 0.f;
    int o = off[m], c = cnt[m];
    for (int i = 0; i < c; i++)
      s += b2f(Hb[(size_t)lst[o + i] * DM + d]);
    Cb[(size_t)m * DM + d] = f2b(s / fmaxf(cntf[m], 1.f));
  }
}

// ---------------------------------------------------------------------------
// LN epilogue — unchanged (verified).
// ---------------------------------------------------------------------------
__global__ __launch_bounds__(256) void ln_epi_kernel(
    const bf16* __restrict__ Hr, const bf16* __restrict__ Gp, const bf16* __restrict__ Up,
    const float* __restrict__ lg, const float* __restrict__ lb, bf16* __restrict__ Hout)
{
  const int b = blockIdx.y;
  const int m0 = blockIdx.x * 8;
  const int c = threadIdx.x;
  __shared__ float red[8];
  float lgv = lg[c], lbv = lb[c];
  int wv = c >> 6, ln = c & 63;
  for (int m = 0; m < 8; m++) {
    size_t idx = ((size_t)b * NN + m0 + m) * DM + c;
    float g = 1.f / (1.f + __expf(-b2f(Gp[idx])));
    float u = geluf(b2f(Up[idx]));
    float hn = b2f(Hr[idx]) + g * u;
    float s1 = hn, s2 = hn * hn;
#pragma unroll
    for (int o = 1; o < 64; o <<= 1) { s1 += __shfl_xor(s1, o, 64); s2 += __shfl_xor(s2, o, 64); }
    if (ln == 0) { red[wv] = s1; red[4 + wv] = s2; }
    __syncthreads();
    float sum = red[0] + red[1] + red[2] + red[3];
    float sq  = red[4] + red[5] + red[6] + red[7];
    float mu = sum * (1.f / DM);
    float var = sq * (1.f / DM) - mu * mu;
    float y = (hn - mu) * rsqrtf(var + 1e-5f) * lgv + lbv;
    Hout[idx] = f2b(y);
    __syncthreads();
  }
}

// rh from Hr via folded vector; rd from h_dep.
__global__ __launch_bounds__(256) void rhrd2_kernel(
    const bf16* __restrict__ Hc, const bf16* __restrict__ hd,
    const float* __restrict__ vha, const float* __restrict__ cha,
    const float* __restrict__ bdw, const float* __restrict__ bdb,
    float* __restrict__ rh, float* __restrict__ rd)
{
  int b = blockIdx.x;
  int t = threadIdx.x;
  int n = t & 127;
  bool isD = t >= 128;
  if (!isD) {
    const bf16* row = Hc + ((size_t)b * NN + n) * DM;
    float s = cha[0];
    for (int k = 0; k < DM; k++) s += b2f(row[k]) * vha[k];
    rh[(size_t)b * NN + n] = s;
  } else {
    const bf16* row = hd + ((size_t)b * NN + n) * DM;
    float s = bdb[0];
    for (int k = 0; k < DM; k++) s += b2f(row[k]) * bdw[k];
    rd[(size_t)b * NN + n] = s;
  }
}

// scores — r8-verified.
__global__ __launch_bounds__(512) void scores_mfma_kernel(
    const bf16* __restrict__ tmp, const bf16* __restrict__ hd,
    const float* __restrict__ rh, const float* __restrict__ rd,
    float* __restrict__ out)
{
  const int b = blockIdx.x;
  const int w = threadIdx.x >> 6;
  const int lane = threadIdx.x & 63;
  const int wr = w >> 1, wc = w & 1;
  const int r16 = lane & 15;
  const int kg = lane >> 4;

  size_t qoff[2], moff[4];
#pragma unroll
  for (int mi = 0; mi < 2; mi++) qoff[mi] = ((size_t)b * NN + wr * 32 + mi * 16 + r16) * DM;
#pragma unroll
  for (int ni = 0; ni < 4; ni++) moff[ni] = ((size_t)b * NN + wc * 64 + ni * 16 + r16) * DM;

  f32x4v zero = {0.f, 0.f, 0.f, 0.f};
  f32x4v acc[2][4];
#pragma unroll
  for (int mi = 0; mi < 2; mi++)
#pragma unroll
    for (int ni = 0; ni < 4; ni++) acc[mi][ni] = zero;

  for (int k0 = 0; k0 < DM; k0 += 32) {
    int k = k0 + kg * 8;
    bf16x8v a[2], bb[4];
#pragma unroll
    for (int mi = 0; mi < 2; mi++) a[mi] = *(const bf16x8v*)(tmp + qoff[mi] + k);
#pragma unroll
    for (int ni = 0; ni < 4; ni++) bb[ni] = *(const bf16x8v*)(hd + moff[ni] + k);
#pragma unroll
    for (int mi = 0; mi < 2; mi++)
#pragma unroll
      for (int ni = 0; ni < 4; ni++)
        acc[mi][ni] = __builtin_amdgcn_mfma_f32_16x16x32_bf16(a[mi], bb[ni], acc[mi][ni], 0, 0, 0);
  }

#pragma unroll
  for (int ni = 0; ni < 4; ni++) {
    int m = wc * 64 + ni * 16 + r16;
    float rhm = rh[b * NN + m];
#pragma unroll
    for (int mi = 0; mi < 2; mi++) {
      int q0 = wr * 32 + mi * 16 + kg * 4;
#pragma unroll
      for (int r = 0; r < 4; r++)
        out[(size_t)b * NN * NN + (size_t)(q0 + r) * NN + m] =
            acc[mi][ni][r] + rhm + rd[b * NN + q0 + r];
    }
  }
}

// ---------------------------------------------------------------------------
extern "C" void kernel_launch(void* const* d_in, const int* in_sizes, int n_in,
                              void* d_out, int out_size, void* d_ws, size_t ws_size,
                              hipStream_t stream) {
  const float* H      = (const float*)d_in[0];
  const int*   ph     = (const int*)  d_in[1];
  const float* mask   = (const float*)d_in[2];
  const float* ha_w   = (const float*)d_in[3];
  const float* ha_b   = (const float*)d_in[4];
  const float* sa_w   = (const float*)d_in[5];
  const float* sa_b   = (const float*)d_in[6];
  const float* ct_w   = (const float*)d_in[7];
  const float* ct_b   = (const float*)d_in[8];
  const float* gate_w = (const float*)d_in[9];
  const float* gate_b = (const float*)d_in[10];
  const float* tr_w   = (const float*)d_in[11];
  const float* tr_b   = (const float*)d_in[12];
  const float* ln_g   = (const float*)d_in[13];
  const float* ln_b   = (const float*)d_in[14];
  const float* ahw    = (const float*)d_in[15];
  const float* ahb    = (const float*)d_in[16];
  const float* adw    = (const float*)d_in[17];
  const float* adb    = (const float*)d_in[18];
  const float* bil    = (const float*)d_in[19];
  const float* bhw    = (const float*)d_in[20];
  const float* bhb    = (const float*)d_in[21];
  const float* bdw    = (const float*)d_in[22];
  const float* bdb    = (const float*)d_in[23];

  const size_t AB = (size_t)BD * NN * DM;  // 8,388,608 elems
  bf16* wsb  = (bf16*)d_ws;
  bf16* Hcur = wsb + 0 * AB;
  bf16* Qa   = wsb + 1 * AB;
  bf16* Ka   = wsb + 2 * AB;   // final: h_dep
  bf16* Va   = wsb + 3 * AB;   // V^T (ha); later Gpre; final: U
  bf16* Qs   = wsb + 4 * AB;
  bf16* Ks   = wsb + 5 * AB;
  bf16* Vs   = wsb + 6 * AB;   // V^T (sa); later Upre
  bf16* mC   = wsb + 7 * AB;
  float* rh  = (float*)(wsb + 8 * AB);
  float* rd  = rh + (size_t)BD * NN;
  float* fgb = rd + (size_t)BD * NN;       // [3][256]
  float* ftb = fgb + 768;                  // [3][256]
  float* fab_bias = ftb + 768;             // [256]
  float* vha = fab_bias + 256;             // [256]
  float* cha = vha + 256;                  // [1]

  // d_out doubles as scratch: 3 regions of AB bf16 each.
  bf16* D0 = (bf16*)d_out;            // CA, then Oa; overwritten by final cvt
  bf16* D1 = D0 + AB;                 // Os; overwritten by final cvt
  bf16* D2 = D0 + 2 * AB;             // weight arena; overwritten by scores
  const size_t RS = 1179648;          // per-round arena stride (bf16 units)
  bf16* adT  = D2 + 3 * RS;           // 65536
  bf16* fabT = adT + 65536;           // 65536

  cvt32to16_kernel<<<dim3(2048), 256, 0, stream>>>(H, Hcur, (int)AB);

  // ---- prologue: all weight transposes + fuses (data-independent) ----
  for (int r = 0; r < RR; r++) {
    bf16* base_r = D2 + (size_t)r * RS;
    bf16* haT = base_r;
    bf16* saT = base_r + 262144;
    bf16* ctT = base_r + 524288;
    bf16* gT  = base_r + 655360;
    bf16* tT  = base_r + 917504;
    TTable T; int base = 0;
    for (int i = 0; i < 3; i++) {
      T.e[i] = { ha_w + ((size_t)r * 4 + i) * 65536, haT + (size_t)i * 65536, 256, base };
      base += 64;
    }
    for (int i = 0; i < 3; i++) {
      T.e[3 + i] = { sa_w + ((size_t)r * 4 + i) * 65536, saT + (size_t)i * 65536, 256, base };
      base += 64;
    }
    T.e[6] = { ct_w + (size_t)r * 131072, ctT, 512, base };                    base += 128;
    T.e[7] = { gate_w + (size_t)r * 262144,             gT,        1024, base }; base += 64;
    T.e[8] = { gate_w + (size_t)r * 262144 + 512 * 256, gT + 512,  1024, base }; base += 64;
    T.e[9] = { tr_w   + (size_t)r * 262144,             tT,        1024, base }; base += 64;
    T.e[10]= { tr_w   + (size_t)r * 262144 + 512 * 256, tT + 512,  1024, base }; base += 64;
    int nent = 11;
    if (r == 0) { T.e[11] = { adw, adT, 256, base }; base += 64; nent = 12; }
    transpose_w_kernel<<<dim3(base), 256, 0, stream>>>(T, nent);
  }
  {
    FJobs F;
    for (int r = 0; r < RR; r++) {
      bf16* gT = D2 + (size_t)r * RS + 655360;
      bf16* tT = D2 + (size_t)r * RS + 917504;
      const float* WoH = ha_w + ((size_t)r * 4 + 3) * 65536;
      const float* WoS = sa_w + ((size_t)r * 4 + 3) * 65536;
      const float* gw = gate_w + (size_t)r * 262144;
      const float* tw = tr_w   + (size_t)r * 262144;
      F.j[r * 4 + 0] = { WoH, gw + 256 * 256, gT, 256, 1024 };
      F.j[r * 4 + 1] = { WoS, gw + 768 * 256, gT, 768, 1024 };
      F.j[r * 4 + 2] = { WoH, tw + 256 * 256, tT, 256, 1024 };
      F.j[r * 4 + 3] = { WoS, tw + 768 * 256, tT, 768, 1024 };
    }
    F.j[12] = { ahw, bil, fabT, 0, 256 };
    wfuse_kernel<<<dim3(16, 13), 256, 0, stream>>>(F);
  }
  bfuse_kernel<<<dim3(7), 256, 0, stream>>>(gate_w, tr_w, gate_b, tr_b,
      ha_b, sa_b, ahw, ahb, bil, bhw, bhb, fgb, ftb, fab_bias, vha, cha);

  // ---- rounds ----
  for (int r = 0; r < RR; r++) {
    bf16* base_r = D2 + (size_t)r * RS;
    bf16* haT = base_r;
    bf16* saT = base_r + 262144;
    bf16* ctT = base_r + 524288;
    bf16* gT  = base_r + 655360;
    bf16* tT  = base_r + 917504;
    const float* hab = ha_b + (size_t)r * 4 * DM;
    const float* sab = sa_b + (size_t)r * 4 * DM;

    child_avg2_kernel<<<dim3(BD), 256, 0, stream>>>(Hcur, ph, mask, D0);

    {
      ProjArgs P;
      P.Hc = Hcur; P.CA = D0; P.gather = ph;
      P.W[0] = haT;          P.bias[0] = hab + 0;   P.out[0] = Qa;
      P.W[1] = haT + 65536;  P.bias[1] = hab + 256; P.out[1] = Ka;
      P.W[2] = haT + 131072; P.bias[2] = hab + 512; P.out[2] = Va;
      P.W[3] = saT;          P.bias[3] = sab + 0;   P.out[3] = Qs;
      P.W[4] = saT + 65536;  P.bias[4] = sab + 256; P.out[4] = Ks;
      P.W[5] = saT + 131072; P.bias[5] = sab + 512; P.out[5] = Vs;
      P.W[6] = ctT;          P.bias[6] = ct_b + (size_t)r * DM; P.out[6] = mC;
      proj_fused_kernel<<<dim3(512), 256, 0, stream>>>(P);
    }

    {
      AttnArgs A = { Qa, Ka, Va, D0, Qs, Ks, Vs, D1 };
      attn2_kernel<<<dim3(NHD, BD, 2), 256, 0, stream>>>(A, ph, mask);
    }

    // gate + tr with folded O-projections, ONE dual dispatch
    {
      DJob J = { Hcur, D0, mC, D1, gT, tT,
                 fgb + (size_t)r * 256, ftb + (size_t)r * 256, Va, Vs, 1024 };
      dualw_gemm_kernel<<<dim3(512), 512, 0, stream>>>(J);
    }

    ln_epi_kernel<<<dim3(16, BD), 256, 0, stream>>>(Hcur, Va, Vs,
        ln_g + (size_t)r * DM, ln_b + (size_t)r * DM, Hcur);
  }

  // ---- final biaffine scorer (h_head folded away), ONE dual dispatch ----
  {
    DJob J = { Hcur, Hcur, Hcur, Hcur, adT, fabT, adb, fab_bias, Ka, Va, 256 };
    dualw_gemm_kernel<<<dim3(512), 512, 0, stream>>>(J);
  }
  rhrd2_kernel<<<dim3(BD), 256, 0, stream>>>(Hcur, Ka, vha, cha, bdw, bdb, rh, rd);
  scores_mfma_kernel<<<dim3(BD), 512, 0, stream>>>(Va, Ka, rh, rd, (float*)d_out + AB);

  cvt16to32_kernel<<<dim3(2048), 256, 0, stream>>>(Hcur, (float*)d_out, (int)AB);
}

// Round 19
// 925.901 us; speedup vs baseline: 1.1176x; 1.0102x over previous
//
#include <hip/hip_runtime.h>
#include <hip/hip_bf16.h>
#include <math.h>

typedef __hip_bfloat16 bf16;
typedef __attribute__((ext_vector_type(8))) short bf16x8v;
typedef __attribute__((ext_vector_type(4))) float f32x4v;

#define BD 256   // batch
#define NN 128   // tokens
#define DM 256   // model dim
#define NHD 4    // heads
#define HDIM 64  // head dim
#define RR 3     // rounds

__device__ __forceinline__ float b2f(bf16 x) { return __bfloat162float(x); }
__device__ __forceinline__ bf16 f2b(float x) { return __float2bfloat16(x); }
__device__ __forceinline__ float geluf(float x) { return 0.5f * x * (1.f + erff(x * 0.70710678118654752f)); }

#define GLOAD16(g, l) __builtin_amdgcn_global_load_lds( \
    (const __attribute__((address_space(1))) void*)(g), \
    (__attribute__((address_space(3))) void*)(l), 16, 0, 0)

// fp32 -> bf16 convert
__global__ __launch_bounds__(256) void cvt32to16_kernel(
    const float* __restrict__ in, bf16* __restrict__ out, int n)
{
  int i = blockIdx.x * 256 + threadIdx.x;
  int stride = gridDim.x * 256;
  for (; i < n; i += stride) out[i] = f2b(in[i]);
}

// ---------------------------------------------------------------------------
// Batched weight transpose: src fp32 [*][256] row-major -> dst bf16 [256][K].
// ---------------------------------------------------------------------------
struct TDesc { const float* src; bf16* dst; int K; int base; };
struct TTable { TDesc e[12]; };

__global__ __launch_bounds__(256) void transpose_w_kernel(TTable T, int nent)
{
  int t = blockIdx.x;
  int ei = 0;
  for (int i = 1; i < nent; i++) if (t >= T.e[i].base) ei = i;
  const float* src = T.e[ei].src;
  bf16* dst = T.e[ei].dst;
  int K = T.e[ei].K;
  int lt = t - T.e[ei].base;
  int nt = lt & 7, kt = lt >> 3;

  __shared__ float tile[32][33];
  int tx = threadIdx.x & 31, ty = threadIdx.x >> 5;
#pragma unroll
  for (int i = 0; i < 4; i++)
    tile[ty + i * 8][tx] = src[(size_t)(kt * 32 + ty + i * 8) * 256 + nt * 32 + tx];
  __syncthreads();
#pragma unroll
  for (int i = 0; i < 4; i++)
    dst[(size_t)(nt * 32 + ty + i * 8) * K + kt * 32 + tx] = f2b(tile[tx][ty + i * 8]);
}

// ---------------------------------------------------------------------------
// Weight-fuse: outT[col][koff+k] = f2b( sum_m A[k][m] * B[m][col] ), 256x256.
// ---------------------------------------------------------------------------
struct FJob { const float* A; const float* B; bf16* outT; int koff; int kst; };
struct FJobs { FJob j[13]; };

__global__ __launch_bounds__(256) void wfuse_kernel(FJobs F)
{
  const FJob jb = F.j[blockIdx.y];
  const int k0 = blockIdx.x * 16;
  const int col = threadIdx.x;
  float acc[16];
#pragma unroll
  for (int i = 0; i < 16; i++) acc[i] = 0.f;
  for (int m = 0; m < 256; m++) {
    float bv = jb.B[(size_t)m * 256 + col];
#pragma unroll
    for (int i = 0; i < 16; i++)
      acc[i] += jb.A[(size_t)(k0 + i) * 256 + m] * bv;
  }
#pragma unroll
  for (int i = 0; i < 16; i++)
    jb.outT[(size_t)col * jb.kst + jb.koff + k0 + i] = f2b(acc[i]);
}

// ---------------------------------------------------------------------------
// Bias-fuse: blocks 0..5 -> fgb/ftb per round; block 6 -> fab_bias, vha, cha.
// ---------------------------------------------------------------------------
__global__ __launch_bounds__(256) void bfuse_kernel(
    const float* gate_w, const float* tr_w, const float* gate_b, const float* tr_b,
    const float* ha_b, const float* sa_b,
    const float* ahw, const float* ahb, const float* bil,
    const float* bhw, const float* bhb,
    float* fgb, float* ftb, float* fab_bias, float* vha, float* cha)
{
  int blk = blockIdx.x, col = threadIdx.x;
  if (blk < 6) {
    int r = blk >> 1; bool isT = blk & 1;
    const float* W  = (isT ? tr_w : gate_w) + (size_t)r * 262144;
    const float* b0 = (isT ? tr_b : gate_b) + (size_t)r * 256;
    const float* boh = ha_b + (size_t)r * 1024 + 768;
    const float* bos = sa_b + (size_t)r * 1024 + 768;
    float acc = b0[col];
    for (int m = 0; m < 256; m++) {
      acc += boh[m] * W[(size_t)(256 + m) * 256 + col];
      acc += bos[m] * W[(size_t)(768 + m) * 256 + col];
    }
    ((isT ? ftb : fgb) + (size_t)r * 256)[col] = acc;
  } else {
    float a1 = 0.f, a2 = 0.f;
    for (int m = 0; m < 256; m++) {
      a1 += ahb[m] * bil[(size_t)m * 256 + col];
      a2 += ahw[(size_t)col * 256 + m] * bhw[m];
    }
    fab_bias[col] = a1;
    vha[col] = a2;
    if (col == 0) {
      float c = bhb[0];
      for (int m = 0; m < 256; m++) c += ahb[m] * bhw[m];
      cha[0] = c;
    }
  }
}

// ---------------------------------------------------------------------------
// proj_fused (r13 champion): 7 GEMMs share A (Hcur) in LDS; W dbuf in LDS.
// grid (512) = (b, colhalf). Block 256 = 4 waves, wave tile 64x64.
// ---------------------------------------------------------------------------
struct ProjArgs {
  const bf16* Hc; const bf16* CA; const int* gather;
  const bf16* W[7];
  const float* bias[7];
  bf16* out[7];
};

__global__ __launch_bounds__(256) void proj_fused_kernel(ProjArgs P)
{
  const int b  = blockIdx.x & 255;
  const int nh = blockIdx.x >> 8;
  const int c0 = nh * 128;
  const int tid = threadIdx.x;
  const int w = tid >> 6;
  const int lane = tid & 63;
  const int wr = w >> 1, wc = w & 1;
  const int r16 = lane & 15;
  const int kg = lane >> 4;

  __shared__ __align__(16) char lds[81920];

  const char* Hb = (const char*)(P.Hc + (size_t)b * NN * DM);

#pragma unroll
  for (int i = 0; i < 16; i++) {
    int row = w * 32 + i * 2 + (lane >> 5);
    int src = row * 512 + (((lane & 31) * 16) ^ ((row & 7) << 4));
    GLOAD16(Hb + src, lds + w * 16384 + i * 1024);
  }

#define STAGE_W(WT, K2, KT, BUF) do { \
    _Pragma("unroll") \
    for (int i_ = 0; i_ < 2; i_++) { \
      int wrow_ = w * 32 + i_ * 16 + (lane >> 2); \
      int slot_ = (lane & 3) ^ ((wrow_ >> 1) & 3); \
      GLOAD16((const char*)(WT) + (size_t)(c0 + wrow_) * (K2) + (KT) * 64 + slot_ * 16, \
              lds + 65536 + (BUF) * 8192 + w * 2048 + i_ * 1024); \
    } } while (0)

  STAGE_W(P.W[0], 512, 0, 0);
  __syncthreads();

  int lrow[4], grow[4];
#pragma unroll
  for (int mi = 0; mi < 4; mi++) {
    lrow[mi] = wr * 64 + mi * 16 + r16;
    int g = P.gather[b * NN + lrow[mi]];
    grow[mi] = min(max(g, 0), NN - 1);
  }
  int wro[4];
#pragma unroll
  for (int ni = 0; ni < 4; ni++) {
    int ct_ = wc * 64 + ni * 16 + r16;
    wro[ni] = ct_ * 64 + ((kg ^ ((ct_ >> 1) & 3)) << 4);
  }

  const bf16* CAb = P.CA + (size_t)b * NN * DM;
  int buf = 0;
  f32x4v zero = {0.f, 0.f, 0.f, 0.f};

#pragma unroll
  for (int j = 0; j < 7; j++) {
    const bool GATH = (j == 1) || (j == 2);
    const bool TR   = (j == 2) || (j == 5);
    const bool ACT  = (j == 6);
    const int NKS = (j == 6) ? 16 : 8;
    const int K2  = (j == 6) ? 1024 : 512;
    const bf16* Wj  = P.W[j];
    const bf16* Wj1 = (j < 6) ? P.W[j + 1] : P.W[j];
    const int  K2n  = (j < 6) ? ((j + 1 == 6) ? 1024 : 512) : K2;

    f32x4v acc[4][4];
#pragma unroll
    for (int mi = 0; mi < 4; mi++)
#pragma unroll
      for (int ni = 0; ni < 4; ni++) acc[mi][ni] = zero;

    for (int kt = 0; kt < NKS; kt++) {
      if (!(j == 6 && kt + 1 == NKS)) {
        const bf16* Wn = (kt + 1 < NKS) ? Wj : Wj1;
        int nkt = (kt + 1 < NKS) ? kt + 1 : 0;
        int nK2 = (kt + 1 < NKS) ? K2 : K2n;
        STAGE_W(Wn, nK2, nkt, buf ^ 1);
      }

      bf16x8v a[4], wv[4];
      if (j == 6 && kt >= 8) {
#pragma unroll
        for (int mi = 0; mi < 4; mi++)
          a[mi] = *(const bf16x8v*)(CAb + (size_t)lrow[mi] * DM + (kt - 8) * 32 + kg * 8);
      } else {
#pragma unroll
        for (int mi = 0; mi < 4; mi++) {
          int ar = GATH ? grow[mi] : lrow[mi];
          int off = ar * 512 + (((kt * 64) + kg * 16) ^ ((ar & 7) << 4));
          a[mi] = *(const bf16x8v*)(lds + off);
        }
      }
#pragma unroll
      for (int ni = 0; ni < 4; ni++)
        wv[ni] = *(const bf16x8v*)(lds + 65536 + buf * 8192 + wro[ni]);

#pragma unroll
      for (int mi = 0; mi < 4; mi++)
#pragma unroll
        for (int ni = 0; ni < 4; ni++)
          acc[mi][ni] = __builtin_amdgcn_mfma_f32_16x16x32_bf16(a[mi], wv[ni], acc[mi][ni], 0, 0, 0);

      __syncthreads();
      buf ^= 1;
    }

    bf16* outj = P.out[j];
    const float* bj = P.bias[j];
#pragma unroll
    for (int ni = 0; ni < 4; ni++) {
      int col = c0 + wc * 64 + ni * 16 + r16;
      float bv = bj ? bj[col] : 0.f;
#pragma unroll
      for (int mi = 0; mi < 4; mi++) {
        int row0 = wr * 64 + mi * 16 + kg * 4;
        if (!TR) {
          size_t base = ((size_t)b * NN + row0) * DM + col;
#pragma unroll
          for (int r = 0; r < 4; r++) {
            float x = acc[mi][ni][r] + bv;
            if (ACT) x = geluf(x);
            outj[base + (size_t)r * DM] = f2b(x);
          }
        } else {
          size_t base = ((size_t)b * DM + col) * NN + row0;
#pragma unroll
          for (int r = 0; r < 4; r++)
            outj[base + r] = f2b(acc[mi][ni][r] + bv);
        }
      }
    }
  }
#undef STAGE_W
}

// ---------------------------------------------------------------------------
// dualw_gemm: TWO GEMMs sharing A (r13-verified). 8 waves: 0-3 -> W0, 4-7 -> W1.
// ---------------------------------------------------------------------------
struct DJob {
  const bf16 *a0, *a1, *a2, *a3;
  const bf16 *W0, *W1;
  const float *b0, *b1;
  bf16 *o0, *o1;
  int K;
};

__global__ __launch_bounds__(512) void dualw_gemm_kernel(DJob jb)
{
  const int b  = blockIdx.x & 255;
  const int nh = blockIdx.x >> 8;
  const int c0 = nh * 128;
  const int tid = threadIdx.x;
  const int w = tid >> 6;
  const int jj = w >> 2;
  const int wsub = w & 3;
  const int wr = wsub >> 1, wc = wsub & 1;
  const int lane = tid & 63;
  const int r16 = lane & 15;
  const int kg = lane >> 4;
  const int K = jb.K;
  const int nk = K >> 5;

  __shared__ __align__(16) char lds[49152];

  const int srow = tid >> 2;
  const int skc  = tid & 3;
  const int sl   = skc ^ ((srow >> 1) & 3);
  const size_t aoff = ((size_t)b * NN + srow) * DM + sl * 8;
  const bf16* w0src = jb.W0 + (size_t)(c0 + srow) * K + sl * 8;
  const bf16* w1src = jb.W1 + (size_t)(c0 + srow) * K + sl * 8;
  const int wbase = w * 1024;

  f32x4v zero = {0.f, 0.f, 0.f, 0.f};
  f32x4v acc[4][4];
#pragma unroll
  for (int mi = 0; mi < 4; mi++)
#pragma unroll
    for (int ni = 0; ni < 4; ni++) acc[mi][ni] = zero;

  int a_ro[4], w_ro[4];
#pragma unroll
  for (int mi = 0; mi < 4; mi++) {
    int row = wr * 64 + mi * 16 + r16;
    a_ro[mi] = row * 64 + ((kg ^ ((row >> 1) & 3)) << 4);
  }
  const int wsel = 16384 + jj * 16384;
#pragma unroll
  for (int ni = 0; ni < 4; ni++) {
    int col = wc * 64 + ni * 16 + r16;
    w_ro[ni] = col * 64 + ((kg ^ ((col >> 1) & 3)) << 4);
  }

  {
    GLOAD16(jb.a0 + aoff, lds + wbase);
    GLOAD16(w0src,        lds + 16384 + wbase);
    GLOAD16(w1src,        lds + 32768 + wbase);
  }
  __syncthreads();

  int cur = 0;
  for (int kt = 0; kt < nk; kt++) {
    if (kt + 1 < nk) {
      int k0 = (kt + 1) << 5;
      int sg = k0 >> 8;
      const bf16* Ab = (sg == 0) ? jb.a0 : ((sg == 1) ? jb.a1 : ((sg == 2) ? jb.a2 : jb.a3));
      int ko = k0 & 255;
      int nb = (cur ^ 1) * 8192;
      GLOAD16(Ab + aoff + ko,  lds + nb + wbase);
      GLOAD16(w0src + k0,      lds + 16384 + nb + wbase);
      GLOAD16(w1src + k0,      lds + 32768 + nb + wbase);
    }

    const char* La = lds + cur * 8192;
    const char* Lw = lds + wsel + cur * 8192;
    bf16x8v a[4], ww[4];
#pragma unroll
    for (int mi = 0; mi < 4; mi++) a[mi] = *(const bf16x8v*)(La + a_ro[mi]);
#pragma unroll
    for (int ni = 0; ni < 4; ni++) ww[ni] = *(const bf16x8v*)(Lw + w_ro[ni]);
#pragma unroll
    for (int mi = 0; mi < 4; mi++)
#pragma unroll
      for (int ni = 0; ni < 4; ni++)
        acc[mi][ni] = __builtin_amdgcn_mfma_f32_16x16x32_bf16(a[mi], ww[ni], acc[mi][ni], 0, 0, 0);

    __syncthreads();
    cur ^= 1;
  }

  bf16* out = jj ? jb.o1 : jb.o0;
  const float* bias = jj ? jb.b1 : jb.b0;
#pragma unroll
  for (int ni = 0; ni < 4; ni++) {
    int col = c0 + wc * 64 + ni * 16 + r16;
    float bv = bias ? bias[col] : 0.f;
#pragma unroll
    for (int mi = 0; mi < 4; mi++) {
      int row0 = wr * 64 + mi * 16 + kg * 4;
      size_t base = ((size_t)b * NN + row0) * DM + col;
#pragma unroll
      for (int r = 0; r < 4; r++)
        out[base + (size_t)r * DM] = f2b(acc[mi][ni][r] + bv);
    }
  }
}

// ---------------------------------------------------------------------------
// Fused dual MFMA attention — r8-verified.
// ---------------------------------------------------------------------------
struct AttnArgs {
  const bf16 *Qa, *Ka, *Va; bf16* Oa;
  const bf16 *Qs, *Ks, *Vs; bf16* Os;
};

__global__ __launch_bounds__(256) void attn2_kernel(
    AttnArgs A, const int* __restrict__ ph, const float* __restrict__ mask)
{
  const int b = blockIdx.y, h = blockIdx.x;
  const bool has_mask = (blockIdx.z == 1);
  const bf16* Qb = has_mask ? A.Qs : A.Qa;
  const bf16* Kb = has_mask ? A.Ks : A.Ka;
  const bf16* Vt = has_mask ? A.Vs : A.Va;
  bf16* Ob       = has_mask ? A.Os : A.Oa;

  const int w = threadIdx.x >> 6;
  const int lane = threadIdx.x & 63;
  const int r16 = lane & 15, kg = lane >> 4;
  const int q0 = w * 32;

  __shared__ bf16 P_lds[4][32 * 128];
  __shared__ int   ph_sh[NN];
  __shared__ float mk_sh[NN];

  if (has_mask && threadIdx.x < NN) {
    ph_sh[threadIdx.x] = ph[(size_t)b * NN + threadIdx.x];
    mk_sh[threadIdx.x] = mask[(size_t)b * NN + threadIdx.x];
  }
  __syncthreads();

  const bf16* Qh = Qb + (size_t)b * NN * DM + (size_t)h * HDIM;
  const bf16* Kh = Kb + (size_t)b * NN * DM + (size_t)h * HDIM;
  const bf16* Vh = Vt + ((size_t)b * DM + (size_t)h * HDIM) * NN;

  f32x4v zero = {0.f, 0.f, 0.f, 0.f};

  f32x4v accs[2][8];
#pragma unroll
  for (int mi = 0; mi < 2; mi++)
#pragma unroll
    for (int ni = 0; ni < 8; ni++) accs[mi][ni] = zero;

#pragma unroll
  for (int ks = 0; ks < 2; ks++) {
    int d = ks * 32 + kg * 8;
    bf16x8v a[2], bb[8];
#pragma unroll
    for (int mi = 0; mi < 2; mi++)
      a[mi] = *(const bf16x8v*)(Qh + (size_t)(q0 + mi * 16 + r16) * DM + d);
#pragma unroll
    for (int ni = 0; ni < 8; ni++)
      bb[ni] = *(const bf16x8v*)(Kh + (size_t)(ni * 16 + r16) * DM + d);
#pragma unroll
    for (int mi = 0; mi < 2; mi++)
#pragma unroll
      for (int ni = 0; ni < 8; ni++)
        accs[mi][ni] = __builtin_amdgcn_mfma_f32_16x16x32_bf16(a[mi], bb[ni], accs[mi][ni], 0, 0, 0);
  }

#pragma unroll
  for (int mi = 0; mi < 2; mi++) {
#pragma unroll
    for (int r = 0; r < 4; r++) {
      int wq = mi * 16 + kg * 4 + r;
      int q_e = q0 + wq;
      float v[8];
      float mx = -3.0e38f;
      int qp = 0; float qm = 1.f;
      if (has_mask) { qp = ph_sh[q_e]; qm = mk_sh[q_e]; }
#pragma unroll
      for (int ni = 0; ni < 8; ni++) {
        float s = accs[mi][ni][r] * 0.125f;
        if (has_mask) {
          int t_e = ni * 16 + r16;
          bool sib = (qp == ph_sh[t_e]) && (q_e != t_e) && (qm > 0.f) && (mk_sh[t_e] > 0.f);
          if (!sib) s = -1e9f;
        }
        v[ni] = s;
        mx = fmaxf(mx, s);
      }
#pragma unroll
      for (int o = 1; o < 16; o <<= 1) mx = fmaxf(mx, __shfl_xor(mx, o, 64));
      float sum = 0.f;
#pragma unroll
      for (int ni = 0; ni < 8; ni++) { v[ni] = __expf(v[ni] - mx); sum += v[ni]; }
#pragma unroll
      for (int o = 1; o < 16; o <<= 1) sum += __shfl_xor(sum, o, 64);
      float inv = 1.f / sum;
      int swz = (wq & 7) << 3;
#pragma unroll
      for (int ni = 0; ni < 8; ni++) {
        int t_e = ni * 16 + r16;
        P_lds[w][(wq * 128 + t_e) ^ swz] = f2b(v[ni] * inv);
      }
    }
  }
  __syncthreads();

  f32x4v acco[2][4];
#pragma unroll
  for (int mi = 0; mi < 2; mi++)
#pragma unroll
    for (int ni = 0; ni < 4; ni++) acco[mi][ni] = zero;

#pragma unroll
  for (int kt = 0; kt < 4; kt++) {
    int t = kt * 32 + kg * 8;
    bf16x8v a[2], bb[4];
#pragma unroll
    for (int mi = 0; mi < 2; mi++) {
      int wqr = mi * 16 + r16;
      int idx = (wqr * 128 + t) ^ ((wqr & 7) << 3);
      a[mi] = *(const bf16x8v*)&P_lds[w][idx];
    }
#pragma unroll
    for (int ni = 0; ni < 4; ni++)
      bb[ni] = *(const bf16x8v*)(Vh + (size_t)(ni * 16 + r16) * NN + t);
#pragma unroll
    for (int mi = 0; mi < 2; mi++)
#pragma unroll
      for (int ni = 0; ni < 4; ni++)
        acco[mi][ni] = __builtin_amdgcn_mfma_f32_16x16x32_bf16(a[mi], bb[ni], acco[mi][ni], 0, 0, 0);
  }

#pragma unroll
  for (int ni = 0; ni < 4; ni++) {
    int d = ni * 16 + r16;
#pragma unroll
    for (int mi = 0; mi < 2; mi++) {
      int qrow = q0 + mi * 16 + kg * 4;
      size_t base = ((size_t)b * NN + qrow) * DM + (size_t)h * HDIM + d;
#pragma unroll
      for (int r = 0; r < 4; r++)
        Ob[base + (size_t)r * DM] = f2b(acco[mi][ni][r]);
    }
  }
}

// ---------------------------------------------------------------------------
// child_avg v2 — unchanged (verified).
// ---------------------------------------------------------------------------
__global__ __launch_bounds__(256) void child_avg2_kernel(
    const bf16* __restrict__ Hr, const int* __restrict__ ph,
    const float* __restrict__ mask, bf16* __restrict__ CA)
{
  const int b = blockIdx.x;
  const int t = threadIdx.x;
  __shared__ int hi[NN];
  __shared__ float mk[NN];
  __shared__ int cnt[NN], off[NN], rnk[NN], lst[NN];
  __shared__ float cntf[NN];

  if (t < NN) {
    int g = ph[(size_t)b * NN + t];
    hi[t] = min(max(g, 0), NN - 1);
    mk[t] = mask[(size_t)b * NN + t];
  }
  __syncthreads();
  if (t < NN) {
    int c = 0, r = 0; float cf = 0.f;
    int me = hi[t];
    for (int j = 0; j < NN; j++) {
      int hj = hi[j];
      c  += (hj == t);
      cf += (hj == t) ? mk[j] : 0.f;
      r  += (j < t) && (hj == me);
    }
    cnt[t] = c; cntf[t] = cf; rnk[t] = r;
  }
  __syncthreads();
  if (t < NN) {
    int o = 0;
    for (int m = 0; m < t; m++) o += cnt[m];
    off[t] = o;
  }
  __syncthreads();
  if (t < NN) lst[off[hi[t]] + rnk[t]] = t;
  __syncthreads();

  const bf16* Hb = Hr + (size_t)b * NN * DM;
  bf16* Cb = CA + (size_t)b * NN * DM;
  const int d = t;
  for (int m = 0; m < NN; m++) {
    float s = 0.f;
    int o = off[m], c = cnt[m];
    for (int i = 0; i < c; i++)
      s += b2f(Hb[(size_t)lst[o + i] * DM + d]);
    Cb[(size_t)m * DM + d] = f2b(s / fmaxf(cntf[m], 1.f));
  }
}

// ---------------------------------------------------------------------------
// LN epilogue: Hn = Hr + sigmoid(Gp)*gelu(Up); LayerNorm -> Hout (bf16).
// fout != nullptr: also write the fp32 LN result (final-round Hr output).
// ---------------------------------------------------------------------------
__global__ __launch_bounds__(256) void ln_epi_kernel(
    const bf16* __restrict__ Hr, const bf16* __restrict__ Gp, const bf16* __restrict__ Up,
    const float* __restrict__ lg, const float* __restrict__ lb,
    bf16* __restrict__ Hout, float* __restrict__ fout)
{
  const int b = blockIdx.y;
  const int m0 = blockIdx.x * 8;
  const int c = threadIdx.x;
  __shared__ float red[8];
  float lgv = lg[c], lbv = lb[c];
  int wv = c >> 6, ln = c & 63;
  for (int m = 0; m < 8; m++) {
    size_t idx = ((size_t)b * NN + m0 + m) * DM + c;
    float g = 1.f / (1.f + __expf(-b2f(Gp[idx])));
    float u = geluf(b2f(Up[idx]));
    float hn = b2f(Hr[idx]) + g * u;
    float s1 = hn, s2 = hn * hn;
#pragma unroll
    for (int o = 1; o < 64; o <<= 1) { s1 += __shfl_xor(s1, o, 64); s2 += __shfl_xor(s2, o, 64); }
    if (ln == 0) { red[wv] = s1; red[4 + wv] = s2; }
    __syncthreads();
    float sum = red[0] + red[1] + red[2] + red[3];
    float sq  = red[4] + red[5] + red[6] + red[7];
    float mu = sum * (1.f / DM);
    float var = sq * (1.f / DM) - mu * mu;
    float y = (hn - mu) * rsqrtf(var + 1e-5f) * lgv + lbv;
    Hout[idx] = f2b(y);
    if (fout) fout[idx] = y;
    __syncthreads();
  }
}

// ---------------------------------------------------------------------------
// scores + fused rh/rd: phase 1 computes rh (from Hc via folded vha/cha) and
// rd (from h_dep via bdw/bdb) into LDS — same scalar loop order as the old
// rhrd2 kernel (bit-identical). Phase 2 = r8-verified scores MFMA.
// grid (BD), block 512.
// ---------------------------------------------------------------------------
__global__ __launch_bounds__(512) void scores_mfma_kernel(
    const bf16* __restrict__ tmp, const bf16* __restrict__ hd,
    const bf16* __restrict__ Hc,
    const float* __restrict__ vha, const float* __restrict__ cha,
    const float* __restrict__ bdw, const float* __restrict__ bdb,
    float* __restrict__ out)
{
  const int b = blockIdx.x;
  __shared__ float rh_l[NN];
  __shared__ float rd_l[NN];

  // ---- phase 1: rh/rd (threads 0..255; same order as old rhrd2) ----
  {
    int t = threadIdx.x;
    if (t < NN) {
      const bf16* row = Hc + ((size_t)b * NN + t) * DM;
      float s = cha[0];
      for (int k = 0; k < DM; k++) s += b2f(row[k]) * vha[k];
      rh_l[t] = s;
    } else if (t < 2 * NN) {
      int n = t - NN;
      const bf16* row = hd + ((size_t)b * NN + n) * DM;
      float s = bdb[0];
      for (int k = 0; k < DM; k++) s += b2f(row[k]) * bdw[k];
      rd_l[n] = s;
    }
  }
  __syncthreads();

  const int w = threadIdx.x >> 6;
  const int lane = threadIdx.x & 63;
  const int wr = w >> 1, wc = w & 1;
  const int r16 = lane & 15;
  const int kg = lane >> 4;

  size_t qoff[2], moff[4];
#pragma unroll
  for (int mi = 0; mi < 2; mi++) qoff[mi] = ((size_t)b * NN + wr * 32 + mi * 16 + r16) * DM;
#pragma unroll
  for (int ni = 0; ni < 4; ni++) moff[ni] = ((size_t)b * NN + wc * 64 + ni * 16 + r16) * DM;

  f32x4v zero = {0.f, 0.f, 0.f, 0.f};
  f32x4v acc[2][4];
#pragma unroll
  for (int mi = 0; mi < 2; mi++)
#pragma unroll
    for (int ni = 0; ni < 4; ni++) acc[mi][ni] = zero;

  for (int k0 = 0; k0 < DM; k0 += 32) {
    int k = k0 + kg * 8;
    bf16x8v a[2], bb[4];
#pragma unroll
    for (int mi = 0; mi < 2; mi++) a[mi] = *(const bf16x8v*)(tmp + qoff[mi] + k);
#pragma unroll
    for (int ni = 0; ni < 4; ni++) bb[ni] = *(const bf16x8v*)(hd + moff[ni] + k);
#pragma unroll
    for (int mi = 0; mi < 2; mi++)
#pragma unroll
      for (int ni = 0; ni < 4; ni++)
        acc[mi][ni] = __builtin_amdgcn_mfma_f32_16x16x32_bf16(a[mi], bb[ni], acc[mi][ni], 0, 0, 0);
  }

#pragma unroll
  for (int ni = 0; ni < 4; ni++) {
    int m = wc * 64 + ni * 16 + r16;
    float rhm = rh_l[m];
#pragma unroll
    for (int mi = 0; mi < 2; mi++) {
      int q0 = wr * 32 + mi * 16 + kg * 4;
#pragma unroll
      for (int r = 0; r < 4; r++)
        out[(size_t)b * NN * NN + (size_t)(q0 + r) * NN + m] =
            acc[mi][ni][r] + rhm + rd_l[q0 + r];
    }
  }
}

// ---------------------------------------------------------------------------
extern "C" void kernel_launch(void* const* d_in, const int* in_sizes, int n_in,
                              void* d_out, int out_size, void* d_ws, size_t ws_size,
                              hipStream_t stream) {
  const float* H      = (const float*)d_in[0];
  const int*   ph     = (const int*)  d_in[1];
  const float* mask   = (const float*)d_in[2];
  const float* ha_w   = (const float*)d_in[3];
  const float* ha_b   = (const float*)d_in[4];
  const float* sa_w   = (const float*)d_in[5];
  const float* sa_b   = (const float*)d_in[6];
  const float* ct_w   = (const float*)d_in[7];
  const float* ct_b   = (const float*)d_in[8];
  const float* gate_w = (const float*)d_in[9];
  const float* gate_b = (const float*)d_in[10];
  const float* tr_w   = (const float*)d_in[11];
  const float* tr_b   = (const float*)d_in[12];
  const float* ln_g   = (const float*)d_in[13];
  const float* ln_b   = (const float*)d_in[14];
  const float* ahw    = (const float*)d_in[15];
  const float* ahb    = (const float*)d_in[16];
  const float* adw    = (const float*)d_in[17];
  const float* adb    = (const float*)d_in[18];
  const float* bil    = (const float*)d_in[19];
  const float* bhw    = (const float*)d_in[20];
  const float* bhb    = (const float*)d_in[21];
  const float* bdw    = (const float*)d_in[22];
  const float* bdb    = (const float*)d_in[23];

  const size_t AB = (size_t)BD * NN * DM;  // 8,388,608 elems
  bf16* wsb  = (bf16*)d_ws;
  bf16* Hcur = wsb + 0 * AB;
  bf16* Qa   = wsb + 1 * AB;
  bf16* Ka   = wsb + 2 * AB;   // final: h_dep
  bf16* Va   = wsb + 3 * AB;   // V^T (ha); later Gpre; final: U
  bf16* Qs   = wsb + 4 * AB;
  bf16* Ks   = wsb + 5 * AB;
  bf16* Vs   = wsb + 6 * AB;   // V^T (sa); later Upre
  bf16* mC   = wsb + 7 * AB;
  float* fgb = (float*)(wsb + 8 * AB);     // [3][256]
  float* ftb = fgb + 768;                  // [3][256]
  float* fab_bias = ftb + 768;             // [256]
  float* vha = fab_bias + 256;             // [256]
  float* cha = vha + 256;                  // [1]

  // d_out doubles as scratch: 3 regions of AB bf16 each.
  bf16* D0 = (bf16*)d_out;            // CA, then Oa; overwritten by final ln fp32
  bf16* D1 = D0 + AB;                 // Os; overwritten by final ln fp32
  bf16* D2 = D0 + 2 * AB;             // weight arena; overwritten by scores
  const size_t RS = 1179648;          // per-round arena stride (bf16 units)
  bf16* adT  = D2 + 3 * RS;           // 65536
  bf16* fabT = adT + 65536;           // 65536

  cvt32to16_kernel<<<dim3(2048), 256, 0, stream>>>(H, Hcur, (int)AB);

  // ---- prologue: all weight transposes + fuses (data-independent) ----
  for (int r = 0; r < RR; r++) {
    bf16* base_r = D2 + (size_t)r * RS;
    bf16* haT = base_r;
    bf16* saT = base_r + 262144;
    bf16* ctT = base_r + 524288;
    bf16* gT  = base_r + 655360;
    bf16* tT  = base_r + 917504;
    TTable T; int base = 0;
    for (int i = 0; i < 3; i++) {
      T.e[i] = { ha_w + ((size_t)r * 4 + i) * 65536, haT + (size_t)i * 65536, 256, base };
      base += 64;
    }
    for (int i = 0; i < 3; i++) {
      T.e[3 + i] = { sa_w + ((size_t)r * 4 + i) * 65536, saT + (size_t)i * 65536, 256, base };
      base += 64;
    }
    T.e[6] = { ct_w + (size_t)r * 131072, ctT, 512, base };                    base += 128;
    T.e[7] = { gate_w + (size_t)r * 262144,             gT,        1024, base }; base += 64;
    T.e[8] = { gate_w + (size_t)r * 262144 + 512 * 256, gT + 512,  1024, base }; base += 64;
    T.e[9] = { tr_w   + (size_t)r * 262144,             tT,        1024, base }; base += 64;
    T.e[10]= { tr_w   + (size_t)r * 262144 + 512 * 256, tT + 512,  1024, base }; base += 64;
    int nent = 11;
    if (r == 0) { T.e[11] = { adw, adT, 256, base }; base += 64; nent = 12; }
    transpose_w_kernel<<<dim3(base), 256, 0, stream>>>(T, nent);
  }
  {
    FJobs F;
    for (int r = 0; r < RR; r++) {
      bf16* gT = D2 + (size_t)r * RS + 655360;
      bf16* tT = D2 + (size_t)r * RS + 917504;
      const float* WoH = ha_w + ((size_t)r * 4 + 3) * 65536;
      const float* WoS = sa_w + ((size_t)r * 4 + 3) * 65536;
      const float* gw = gate_w + (size_t)r * 262144;
      const float* tw = tr_w   + (size_t)r * 262144;
      F.j[r * 4 + 0] = { WoH, gw + 256 * 256, gT, 256, 1024 };
      F.j[r * 4 + 1] = { WoS, gw + 768 * 256, gT, 768, 1024 };
      F.j[r * 4 + 2] = { WoH, tw + 256 * 256, tT, 256, 1024 };
      F.j[r * 4 + 3] = { WoS, tw + 768 * 256, tT, 768, 1024 };
    }
    F.j[12] = { ahw, bil, fabT, 0, 256 };
    wfuse_kernel<<<dim3(16, 13), 256, 0, stream>>>(F);
  }
  bfuse_kernel<<<dim3(7), 256, 0, stream>>>(gate_w, tr_w, gate_b, tr_b,
      ha_b, sa_b, ahw, ahb, bil, bhw, bhb, fgb, ftb, fab_bias, vha, cha);

  // ---- rounds ----
  for (int r = 0; r < RR; r++) {
    bf16* base_r = D2 + (size_t)r * RS;
    bf16* haT = base_r;
    bf16* saT = base_r + 262144;
    bf16* ctT = base_r + 524288;
    bf16* gT  = base_r + 655360;
    bf16* tT  = base_r + 917504;
    const float* hab = ha_b + (size_t)r * 4 * DM;
    const float* sab = sa_b + (size_t)r * 4 * DM;

    child_avg2_kernel<<<dim3(BD), 256, 0, stream>>>(Hcur, ph, mask, D0);

    {
      ProjArgs P;
      P.Hc = Hcur; P.CA = D0; P.gather = ph;
      P.W[0] = haT;          P.bias[0] = hab + 0;   P.out[0] = Qa;
      P.W[1] = haT + 65536;  P.bias[1] = hab + 256; P.out[1] = Ka;
      P.W[2] = haT + 131072; P.bias[2] = hab + 512; P.out[2] = Va;
      P.W[3] = saT;          P.bias[3] = sab + 0;   P.out[3] = Qs;
      P.W[4] = saT + 65536;  P.bias[4] = sab + 256; P.out[4] = Ks;
      P.W[5] = saT + 131072; P.bias[5] = sab + 512; P.out[5] = Vs;
      P.W[6] = ctT;          P.bias[6] = ct_b + (size_t)r * DM; P.out[6] = mC;
      proj_fused_kernel<<<dim3(512), 256, 0, stream>>>(P);
    }

    {
      AttnArgs A = { Qa, Ka, Va, D0, Qs, Ks, Vs, D1 };
      attn2_kernel<<<dim3(NHD, BD, 2), 256, 0, stream>>>(A, ph, mask);
    }

    // gate + tr with folded O-projections, ONE dual dispatch
    {
      DJob J = { Hcur, D0, mC, D1, gT, tT,
                 fgb + (size_t)r * 256, ftb + (size_t)r * 256, Va, Vs, 1024 };
      dualw_gemm_kernel<<<dim3(512), 512, 0, stream>>>(J);
    }

    // final round: ln_epi also writes the fp32 Hr output directly
    float* fout = (r == RR - 1) ? (float*)d_out : nullptr;
    ln_epi_kernel<<<dim3(16, BD), 256, 0, stream>>>(Hcur, Va, Vs,
        ln_g + (size_t)r * DM, ln_b + (size_t)r * DM, Hcur, fout);
  }

  // ---- final biaffine scorer (h_head folded away), ONE dual dispatch ----
  {
    DJob J = { Hcur, Hcur, Hcur, Hcur, adT, fabT, adb, fab_bias, Ka, Va, 256 };
    dualw_gemm_kernel<<<dim3(512), 512, 0, stream>>>(J);
  }
  scores_mfma_kernel<<<dim3(BD), 512, 0, stream>>>(Va, Ka, Hcur,
      vha, cha, bdw, bdb, (float*)d_out + AB);
}